// Round 6
// baseline (265.929 us; speedup 1.0000x reference)
//
#include <hip/hip_runtime.h>
#include <hip/hip_bf16.h>

// ---------------------------------------------------------------------------
// MultiHeadSelfAttention (Swin rel-pos bias), B=64 S=196 D=768 H=12 pd=64
// f2b ; wtrans(stacked) ; bias_pre(bf16) ; gemm8p QKV (256^2 8-phase) ;
// attn (S^T, 4-tile chunks, 75KB LDS, 2 blocks/CU) ; gemm8p O-proj
// ---------------------------------------------------------------------------

typedef __bf16 bf16x8 __attribute__((ext_vector_type(8)));
typedef __bf16 bf16x4 __attribute__((ext_vector_type(4)));
typedef float  f32x4  __attribute__((ext_vector_type(4)));

#define MROWS 12544
#define DDIM  768
#define NHEAD 12
#define SEQ   196
#define KSTR  68         // Ksm row stride (136B): breaks the 4(lr+lg) 8-way bank pattern
#define VSTR  232        // Vts row stride
#define PSTR  68         // per-wave P row stride (chunk-relative, 64 cols + pad)

static __device__ __forceinline__ f32x4 MFMA(bf16x8 a, bf16x8 b, f32x4 c) {
    return __builtin_amdgcn_mfma_f32_16x16x32_bf16(a, b, c, 0, 0, 0);
}

static __device__ __forceinline__ void gload16(const __bf16* g, __bf16* l) {
    __builtin_amdgcn_global_load_lds(
        (const __attribute__((address_space(1))) void*)(g),
        (__attribute__((address_space(3))) void*)(l),
        16, 0, 0);
}

// ---------------- prep: fp32 -> bf16 ---------------------------------------
__global__ __launch_bounds__(256) void f2b(const float* __restrict__ in,
                                           __bf16* __restrict__ out) {
    size_t i = ((size_t)blockIdx.x * 256 + threadIdx.x) * 8;
    f32x4 a = *(const f32x4*)&in[i];
    f32x4 b = *(const f32x4*)&in[i + 4];
    bf16x8 o;
    o[0] = (__bf16)a[0]; o[1] = (__bf16)a[1]; o[2] = (__bf16)a[2]; o[3] = (__bf16)a[3];
    o[4] = (__bf16)b[0]; o[5] = (__bf16)b[1]; o[6] = (__bf16)b[2]; o[7] = (__bf16)b[3];
    *(bf16x8*)&out[i] = o;
}

// ---------------- prep: W [k][n] fp32 -> Wt [n][k] bf16 --------------------
__global__ __launch_bounds__(256) void wtrans(const float* __restrict__ W0, const float* __restrict__ W1,
                                              const float* __restrict__ W2, const float* __restrict__ W3,
                                              __bf16* __restrict__ T0, __bf16* __restrict__ T1,
                                              __bf16* __restrict__ T2, __bf16* __restrict__ T3) {
    const float* Ws[4] = {W0, W1, W2, W3};
    __bf16*      Ts[4] = {T0, T1, T2, T3};
    const float* W = Ws[blockIdx.z];
    __bf16*      T = Ts[blockIdx.z];
    __shared__ __bf16 t[32][33];
    int k0 = blockIdx.x * 32, n0 = blockIdx.y * 32;
    int c = threadIdx.x & 31, r = threadIdx.x >> 5;
#pragma unroll
    for (int i = 0; i < 4; ++i)
        t[r + i * 8][c] = (__bf16)W[(size_t)(k0 + r + i * 8) * DDIM + n0 + c];
    __syncthreads();
#pragma unroll
    for (int i = 0; i < 4; ++i)
        T[(size_t)(n0 + r + i * 8) * DDIM + k0 + c] = t[c][r + i * 8];
}

// ---------------- prep: bias[h][q][k] = table[rel[q][k]][h]  (bf16) --------
__global__ __launch_bounds__(256) void bias_pre(const float* __restrict__ table,
                                                const int* __restrict__ rel,
                                                __bf16* __restrict__ biasH) {
    int i = blockIdx.x * 256 + threadIdx.x;
    if (i < NHEAD * SEQ * SEQ) {
        int h = i / (SEQ * SEQ), qk = i - h * (SEQ * SEQ);
        biasH[i] = (__bf16)table[rel[qk] * NHEAD + h];
    }
}

// ---------------------------------------------------------------------------
// 256x256 8-phase GEMM: C = A[M][768] * Bt[N][768]^T + bias
// ---------------------------------------------------------------------------
template <typename OutT, int NMAT>
__global__ __launch_bounds__(512, 2) void gemm8p(const __bf16* __restrict__ A,
                                                 const __bf16* __restrict__ Bt,
                                                 const float* __restrict__ bz0,
                                                 const float* __restrict__ bz1,
                                                 const float* __restrict__ bz2,
                                                 OutT* __restrict__ Cz0,
                                                 OutT* __restrict__ Cz1,
                                                 OutT* __restrict__ Cz2,
                                                 int nbn) {
    __shared__ __bf16 As[3][256 * 64];   // 3 x 32 KiB
    __shared__ __bf16 Bs[2][256 * 64];   // 2 x 32 KiB

    const int nwg = gridDim.x, orig = blockIdx.x;
    const int qq = nwg >> 3, r8 = nwg & 7, xcd = orig & 7, lin = orig >> 3;
    const int wg = (xcd < r8 ? xcd * (qq + 1) : r8 * (qq + 1) + (xcd - r8) * qq) + lin;
    const int bm = wg / nbn, bn = wg - bm * nbn;
    const int m0 = bm * 256, n0g = bn * 256;

    const int tid = threadIdx.x, w = tid >> 6, l = tid & 63;
    const int lr = l & 15, lg = l >> 4;
    const int wrow = (w >> 2) * 128;
    const int wcol = (w & 3) * 64;

    const int srow = w * 8 + (l >> 3);
    const int scol = ((l & 7) ^ ((l >> 3) & 7)) * 8;
    const __bf16* gA = A  + (size_t)(m0 + srow) * DDIM + scol;
    const __bf16* gB = Bt + (size_t)(n0g + srow) * DDIM + scol;

#define STAGE_A(slot, h, kt)                                                      \
    do {                                                                          \
        gload16(gA + ((h) * 128 + 0) * DDIM + (kt) * 64,                          \
                &As[slot][(h) * 8192 + 0 + w * 512]);                             \
        gload16(gA + ((h) * 128 + 64) * DDIM + (kt) * 64,                         \
                &As[slot][(h) * 8192 + 4096 + w * 512]);                          \
    } while (0)
#define STAGE_B(slot, h, kt)                                                      \
    do {                                                                          \
        gload16(gB + ((h) * 128 + 0) * DDIM + (kt) * 64,                          \
                &Bs[slot][(h) * 8192 + 0 + w * 512]);                             \
        gload16(gB + ((h) * 128 + 64) * DDIM + (kt) * 64,                         \
                &Bs[slot][(h) * 8192 + 4096 + w * 512]);                          \
    } while (0)

#define AF(slot, mf, ks)                                                          \
    (*(const bf16x8*)&As[slot][(w >> 2) * 8192 + ((mf) * 16 + lr) * 64 +          \
                              ((((ks) * 4 + lg) ^ (lr & 7))) * 8])
#define BF(slot, nf, ks)                                                          \
    (*(const bf16x8*)&Bs[slot][((w & 3) >> 1) * 8192 +                            \
                              ((w & 1) * 64 + (nf) * 16 + lr) * 64 +              \
                              ((((ks) * 4 + lg) ^ (lr & 7))) * 8])

    f32x4 acc[8][4];
#pragma unroll
    for (int i = 0; i < 8; ++i)
#pragma unroll
        for (int j = 0; j < 4; ++j) acc[i][j] = (f32x4){0.f, 0.f, 0.f, 0.f};

    bf16x8 a0, a1, a2, a3;
    bf16x8 bfr00, bfr01, bfr10, bfr11, bfr20, bfr21, bfr30, bfr31;

#define DSLOAD_A(slot, mf0)                                                       \
    a0 = AF(slot, mf0, 0); a1 = AF(slot, mf0, 1);                                 \
    a2 = AF(slot, (mf0) + 1, 0); a3 = AF(slot, (mf0) + 1, 1);
#define DSLOAD_B(slot)                                                            \
    bfr00 = BF(slot, 0, 0); bfr01 = BF(slot, 0, 1);                               \
    bfr10 = BF(slot, 1, 0); bfr11 = BF(slot, 1, 1);                               \
    bfr20 = BF(slot, 2, 0); bfr21 = BF(slot, 2, 1);                               \
    bfr30 = BF(slot, 3, 0); bfr31 = BF(slot, 3, 1);
#define BARRIER_IN()                                                              \
    __builtin_amdgcn_sched_barrier(0);                                            \
    __builtin_amdgcn_s_barrier();                                                 \
    asm volatile("s_waitcnt lgkmcnt(0)" ::: "memory");                            \
    __builtin_amdgcn_sched_barrier(0);                                            \
    __builtin_amdgcn_s_setprio(1);
#define BARRIER_OUT()                                                             \
    __builtin_amdgcn_s_setprio(0);                                                \
    __builtin_amdgcn_sched_barrier(0);                                            \
    __builtin_amdgcn_s_barrier();                                                 \
    __builtin_amdgcn_sched_barrier(0);
#define MFMACL(mf0)                                                               \
    acc[mf0][0] = MFMA(a0, bfr00, acc[mf0][0]);                                   \
    acc[mf0][0] = MFMA(a1, bfr01, acc[mf0][0]);                                   \
    acc[(mf0) + 1][0] = MFMA(a2, bfr00, acc[(mf0) + 1][0]);                       \
    acc[(mf0) + 1][0] = MFMA(a3, bfr01, acc[(mf0) + 1][0]);                       \
    acc[mf0][1] = MFMA(a0, bfr10, acc[mf0][1]);                                   \
    acc[mf0][1] = MFMA(a1, bfr11, acc[mf0][1]);                                   \
    acc[(mf0) + 1][1] = MFMA(a2, bfr10, acc[(mf0) + 1][1]);                       \
    acc[(mf0) + 1][1] = MFMA(a3, bfr11, acc[(mf0) + 1][1]);                       \
    acc[mf0][2] = MFMA(a0, bfr20, acc[mf0][2]);                                   \
    acc[mf0][2] = MFMA(a1, bfr21, acc[mf0][2]);                                   \
    acc[(mf0) + 1][2] = MFMA(a2, bfr20, acc[(mf0) + 1][2]);                       \
    acc[(mf0) + 1][2] = MFMA(a3, bfr21, acc[(mf0) + 1][2]);                       \
    acc[mf0][3] = MFMA(a0, bfr30, acc[mf0][3]);                                   \
    acc[mf0][3] = MFMA(a1, bfr31, acc[mf0][3]);                                   \
    acc[(mf0) + 1][3] = MFMA(a2, bfr30, acc[(mf0) + 1][3]);                       \
    acc[(mf0) + 1][3] = MFMA(a3, bfr31, acc[(mf0) + 1][3]);

    STAGE_A(0, 0, 0); STAGE_A(0, 1, 0); STAGE_B(0, 0, 0); STAGE_B(0, 1, 0);
    STAGE_A(1, 0, 1); STAGE_A(1, 1, 1); STAGE_B(1, 0, 1); STAGE_B(1, 1, 1);
    asm volatile("s_waitcnt vmcnt(8)" ::: "memory");
    __builtin_amdgcn_s_barrier();
    __builtin_amdgcn_sched_barrier(0);

#pragma unroll
    for (int i = 0; i < 6; ++i) {
        const int s0 = (2 * i) % 3, s1 = (2 * i + 1) % 3, s2 = (2 * i + 2) % 3;
        // ---- phase 0
        DSLOAD_A(s0, 0); DSLOAD_B(0);
        if (i < 5) STAGE_A(s2, 0, 2 * i + 2);
        BARRIER_IN(); MFMACL(0); BARRIER_OUT();
        // ---- phase 1
        DSLOAD_A(s0, 2);
        if (i < 5) STAGE_A(s2, 1, 2 * i + 2);
        BARRIER_IN(); MFMACL(2); BARRIER_OUT();
        // ---- phase 2
        DSLOAD_A(s0, 4);
        if (i < 5) STAGE_B(0, 0, 2 * i + 2);
        BARRIER_IN(); MFMACL(4); BARRIER_OUT();
        // ---- phase 3
        DSLOAD_A(s0, 6);
        if (i < 5) {
            STAGE_B(0, 1, 2 * i + 2);
            asm volatile("s_waitcnt vmcnt(8)" ::: "memory");
        } else {
            asm volatile("s_waitcnt vmcnt(0)" ::: "memory");
        }
        BARRIER_IN(); MFMACL(6); BARRIER_OUT();
        // ---- phase 4
        DSLOAD_A(s1, 0); DSLOAD_B(1);
        if (i < 5) STAGE_A(s0, 0, 2 * i + 3);
        BARRIER_IN(); MFMACL(0); BARRIER_OUT();
        // ---- phase 5
        DSLOAD_A(s1, 2);
        if (i < 5) STAGE_A(s0, 1, 2 * i + 3);
        BARRIER_IN(); MFMACL(2); BARRIER_OUT();
        // ---- phase 6
        DSLOAD_A(s1, 4);
        if (i < 5) STAGE_B(1, 0, 2 * i + 3);
        BARRIER_IN(); MFMACL(4); BARRIER_OUT();
        // ---- phase 7
        DSLOAD_A(s1, 6);
        if (i < 5) {
            STAGE_B(1, 1, 2 * i + 3);
            asm volatile("s_waitcnt vmcnt(8)" ::: "memory");
        }
        BARRIER_IN(); MFMACL(6); BARRIER_OUT();
    }

    const int mat = (NMAT == 1) ? 0 : (n0g / DDIM);
    const int colbase = n0g - mat * DDIM + wcol;
    const float* bz = (mat == 0) ? bz0 : (mat == 1 ? bz1 : bz2);
    OutT* Cc = (mat == 0) ? Cz0 : (mat == 1 ? Cz1 : Cz2);
#pragma unroll
    for (int nf = 0; nf < 4; ++nf) {
        const int col = colbase + nf * 16 + lr;
        const float bb = bz[col];
#pragma unroll
        for (int mf = 0; mf < 8; ++mf) {
            const int row = m0 + wrow + mf * 16 + lg * 4;
#pragma unroll
            for (int r2 = 0; r2 < 4; ++r2)
                Cc[(size_t)(row + r2) * DDIM + col] = (OutT)(acc[mf][nf][r2] + bb);
        }
    }
#undef STAGE_A
#undef STAGE_B
#undef AF
#undef BF
#undef DSLOAD_A
#undef DSLOAD_B
#undef BARRIER_IN
#undef BARRIER_OUT
#undef MFMACL
}

// ---------------- attn chunk: QK^T tiles T0..T0+NTC-1, PV kt KT0..+NKT-1 ---
template <int T0, int NTC, int KT0, int NKT, bool REZERO>
static __device__ __forceinline__ void attn_chunk(
    const __bf16* Ksm, const __bf16* Vts, __bf16* Pw, const __bf16* bh,
    int qrow, int lr, int lg, bf16x8 bq0, bf16x8 bq1,
    float& m_run, float& s_run, f32x4* oa) {
    f32x4 sc[NTC];
    __builtin_amdgcn_s_setprio(1);
#pragma unroll
    for (int tt = 0; tt < NTC; ++tt) {
        const int t = T0 + tt;
        bf16x8 kf0 = *(const bf16x8*)&Ksm[(t * 16 + lr) * KSTR + lg * 8];
        bf16x8 kf1 = *(const bf16x8*)&Ksm[(t * 16 + lr) * KSTR + 32 + lg * 8];
        f32x4 a = {0.f, 0.f, 0.f, 0.f};
        a = MFMA(kf0, bq0, a);
        a = MFMA(kf1, bq1, a);
        sc[tt] = a;
    }
    __builtin_amdgcn_s_setprio(0);
    float mc = -1e30f;
#pragma unroll
    for (int tt = 0; tt < NTC; ++tt) {
        const int t = T0 + tt;
        const bool val4 = (t < 12) || (lg == 0);
        float bb[4] = {0.f, 0.f, 0.f, 0.f};
        if (val4) {
            bf16x4 b4 = *(const bf16x4*)&bh[(size_t)qrow * SEQ + t * 16 + lg * 4];
#pragma unroll
            for (int r = 0; r < 4; ++r) bb[r] = (float)b4[r];
        }
#pragma unroll
        for (int r = 0; r < 4; ++r) {
            float v = val4 ? (sc[tt][r] * 0.125f + bb[r]) : -1e30f;
            sc[tt][r] = v;
            mc = fmaxf(mc, v);
        }
    }
    mc = fmaxf(mc, __shfl_xor(mc, 16));
    mc = fmaxf(mc, __shfl_xor(mc, 32));
    const float mnew = fmaxf(m_run, mc);
    const float fsc = __expf(m_run - mnew);
    m_run = mnew;
    s_run *= fsc;
#pragma unroll
    for (int i = 0; i < 4; ++i)
#pragma unroll
        for (int r = 0; r < 4; ++r) oa[i][r] *= fsc;
    float ps = 0.f;
#pragma unroll
    for (int tt = 0; tt < NTC; ++tt) {
        bf16x4 pk;
#pragma unroll
        for (int r = 0; r < 4; ++r) {
            float p = __expf(sc[tt][r] - m_run);
            ps += p;
            pk[r] = (__bf16)p;
        }
        *(bf16x4*)&Pw[lr * PSTR + tt * 16 + lg * 4] = pk;   // chunk-relative cols
    }
    ps += __shfl_xor(ps, 16);
    ps += __shfl_xor(ps, 32);
    s_run += ps;
    if (REZERO) {   // zero rel cols 16..31 (kk pad) before PV reads them
        bf16x4 z4 = {(__bf16)0.f, (__bf16)0.f, (__bf16)0.f, (__bf16)0.f};
        *(bf16x4*)&Pw[lr * PSTR + 16 + lg * 4] = z4;
    }
    __builtin_amdgcn_s_setprio(1);
#pragma unroll
    for (int ktl = 0; ktl < NKT; ++ktl) {
        bf16x8 pf = *(const bf16x8*)&Pw[lr * PSTR + ktl * 32 + lg * 8];
#pragma unroll
        for (int nt = 0; nt < 4; ++nt) {
            bf16x8 vf = *(const bf16x8*)&Vts[(nt * 16 + lr) * VSTR + (KT0 + ktl) * 32 + lg * 8];
            oa[nt] = MFMA(vf, pf, oa[nt]);
        }
    }
    __builtin_amdgcn_s_setprio(0);
}

// ---------------- fused attention: 75 KB LDS, 2 blocks/CU ------------------
__global__ __launch_bounds__(512, 4) void attn_kernel(const __bf16* __restrict__ Qg,
                                                      const __bf16* __restrict__ Kg,
                                                      const __bf16* __restrict__ Vg,
                                                      const __bf16* __restrict__ biasH,
                                                      __bf16* __restrict__ Og) {
    __shared__ __bf16 Ksm[208 * KSTR];      // 28.3 KB
    __shared__ __bf16 Vts[64 * VSTR];       // 29.7 KB
    __shared__ __bf16 Psm[8 * 16 * PSTR];   // 17.4 KB  (per-wave [16][68], chunk-relative)

    const int b = blockIdx.x, h = blockIdx.y;
    const int tid = threadIdx.x, w = tid >> 6, l = tid & 63;
    const int lr = l & 15, lg = l >> 4;
    const size_t base = (size_t)(b * SEQ) * DDIM + h * 64;
    const __bf16* Kb = Kg + base;
    const __bf16* Vb = Vg + base;
    const __bf16* Qb = Qg + base;
    const __bf16* bh = biasH + (size_t)h * (SEQ * SEQ);

    // stage K rows (16B chunks), cols 0..63
    for (int c = tid; c < SEQ * 8; c += 512) {
        int kk = c >> 3, d8 = (c & 7) << 3;
        *(bf16x8*)&Ksm[kk * KSTR + d8] = *(const bf16x8*)&Kb[(size_t)kk * DDIM + d8];
    }
    // zero K pad rows 196..207
    for (int c = tid; c < 12 * 8; c += 512) {
        int kk = SEQ + (c >> 3), d8 = (c & 7) << 3;
        *(uint4*)&Ksm[kk * KSTR + d8] = make_uint4(0u, 0u, 0u, 0u);
    }
    // stage V transposed
    for (int c = tid; c < SEQ * 8; c += 512) {
        int kk = c >> 3, d8 = (c & 7) << 3;
        bf16x8 vv = *(const bf16x8*)&Vb[(size_t)kk * DDIM + d8];
#pragma unroll
        for (int j = 0; j < 8; ++j) Vts[(d8 + j) * VSTR + kk] = vv[j];
    }
    // zero Vt cols 196..223
    for (int c = tid; c < 64 * 28; c += 512)
        Vts[(c / 28) * VSTR + SEQ + (c % 28)] = (__bf16)0.f;
    __syncthreads();

    __bf16* Pw = &Psm[w * 16 * PSTR];

    for (int qt = w; qt < 13; qt += 8) {
        const int q0 = qt * 16;
        const int q = q0 + lr;
        const int qrow = min(q, SEQ - 1);
        bf16x8 bq0 = *(const bf16x8*)&Qb[(size_t)qrow * DDIM + lg * 8];
        bf16x8 bq1 = *(const bf16x8*)&Qb[(size_t)qrow * DDIM + 32 + lg * 8];

        float m_run = -1e30f, s_run = 0.f;
        f32x4 oa[4];
#pragma unroll
        for (int i = 0; i < 4; ++i) oa[i] = (f32x4){0.f, 0.f, 0.f, 0.f};

        attn_chunk<0, 4, 0, 2, false>(Ksm, Vts, Pw, bh, qrow, lr, lg, bq0, bq1, m_run, s_run, oa);
        attn_chunk<4, 4, 2, 2, false>(Ksm, Vts, Pw, bh, qrow, lr, lg, bq0, bq1, m_run, s_run, oa);
        attn_chunk<8, 4, 4, 2, false>(Ksm, Vts, Pw, bh, qrow, lr, lg, bq0, bq1, m_run, s_run, oa);
        attn_chunk<12, 1, 6, 1, true>(Ksm, Vts, Pw, bh, qrow, lr, lg, bq0, bq1, m_run, s_run, oa);

        const float inv = 1.f / s_run;
        if (q < SEQ) {
#pragma unroll
            for (int nt = 0; nt < 4; ++nt) {
                bf16x4 ok;
#pragma unroll
                for (int r = 0; r < 4; ++r) ok[r] = (__bf16)(oa[nt][r] * inv);
                *(bf16x4*)&Og[(size_t)(b * SEQ + q) * DDIM + h * 64 + nt * 16 + lg * 4] = ok;
            }
        }
    }
}

// ---------------------------------------------------------------------------
extern "C" void kernel_launch(void* const* d_in, const int* in_sizes, int n_in,
                              void* d_out, int out_size, void* d_ws, size_t ws_size,
                              hipStream_t stream) {
    const float* x     = (const float*)d_in[0];
    const float* Wq    = (const float*)d_in[1];
    const float* bq    = (const float*)d_in[2];
    const float* Wk    = (const float*)d_in[3];
    const float* bk    = (const float*)d_in[4];
    const float* Wv    = (const float*)d_in[5];
    const float* bv    = (const float*)d_in[6];
    const float* Wo    = (const float*)d_in[7];
    const float* bo    = (const float*)d_in[8];
    const float* table = (const float*)d_in[9];
    const int*   rel   = (const int*)d_in[10];
    float* out = (float*)d_out;

    char* ws = (char*)d_ws;
    auto alloc = [&](size_t bytes) {
        char* p = ws;
        ws += (bytes + 255) & ~(size_t)255;
        return p;
    };
    const size_t mat = (size_t)MROWS * DDIM * sizeof(__bf16);
    __bf16* xb    = (__bf16*)alloc(mat);
    __bf16* Tqkv  = (__bf16*)alloc((size_t)3 * DDIM * DDIM * 2);
    __bf16* To    = (__bf16*)alloc((size_t)DDIM * DDIM * 2);
    __bf16* Qb    = (__bf16*)alloc(mat);
    __bf16* Kb    = (__bf16*)alloc(mat);
    __bf16* Vb    = (__bf16*)alloc(mat);
    __bf16* AO    = (__bf16*)alloc(mat);
    __bf16* biasH = (__bf16*)alloc((size_t)NHEAD * SEQ * SEQ * 2);

    f2b<<<dim3(4704), 256, 0, stream>>>(x, xb);
    wtrans<<<dim3(24, 24, 4), 256, 0, stream>>>(Wq, Wk, Wv, Wo,
                                                Tqkv, Tqkv + (size_t)DDIM * DDIM,
                                                Tqkv + (size_t)2 * DDIM * DDIM, To);
    bias_pre<<<dim3(1801), 256, 0, stream>>>(table, rel, biasH);

    gemm8p<__bf16, 3><<<dim3(441), 512, 0, stream>>>(xb, Tqkv, bq, bk, bv,
                                                     Qb, Kb, Vb, 9);
    attn_kernel<<<dim3(64, 12), 512, 0, stream>>>(Qb, Kb, Vb, biasH, AO);
    gemm8p<float, 1><<<dim3(147), 512, 0, stream>>>(AO, To, bo, bo, bo,
                                                    out, out, out, 3);
}

// Round 7
// 177.768 us; speedup vs baseline: 1.4959x; 1.4959x over previous
//
#include <hip/hip_runtime.h>
#include <hip/hip_bf16.h>

// ---------------------------------------------------------------------------
// MultiHeadSelfAttention (Swin rel-pos bias), B=64 S=196 D=768 H=12 pd=64
// f2b ; wtrans(stacked) ; bias_pre(bf16) ; gemm8p QKV (256^2 8-phase) ;
// attn (S^T, 4-tile chunks, 75KB LDS, 2 blocks/CU, 128-reg no-spill) ; gemm8p O
// ---------------------------------------------------------------------------

typedef __bf16 bf16x8 __attribute__((ext_vector_type(8)));
typedef __bf16 bf16x4 __attribute__((ext_vector_type(4)));
typedef float  f32x4  __attribute__((ext_vector_type(4)));

#define MROWS 12544
#define DDIM  768
#define NHEAD 12
#define SEQ   196
#define KSTR  68         // Ksm row stride (136B): breaks the 8-way bank pattern
#define VSTR  232        // Vts row stride
#define PSTR  68         // per-wave P row stride (chunk-relative, 64 cols + pad)

static __device__ __forceinline__ f32x4 MFMA(bf16x8 a, bf16x8 b, f32x4 c) {
    return __builtin_amdgcn_mfma_f32_16x16x32_bf16(a, b, c, 0, 0, 0);
}

static __device__ __forceinline__ void gload16(const __bf16* g, __bf16* l) {
    __builtin_amdgcn_global_load_lds(
        (const __attribute__((address_space(1))) void*)(g),
        (__attribute__((address_space(3))) void*)(l),
        16, 0, 0);
}

// ---------------- prep: fp32 -> bf16 ---------------------------------------
__global__ __launch_bounds__(256) void f2b(const float* __restrict__ in,
                                           __bf16* __restrict__ out) {
    size_t i = ((size_t)blockIdx.x * 256 + threadIdx.x) * 8;
    f32x4 a = *(const f32x4*)&in[i];
    f32x4 b = *(const f32x4*)&in[i + 4];
    bf16x8 o;
    o[0] = (__bf16)a[0]; o[1] = (__bf16)a[1]; o[2] = (__bf16)a[2]; o[3] = (__bf16)a[3];
    o[4] = (__bf16)b[0]; o[5] = (__bf16)b[1]; o[6] = (__bf16)b[2]; o[7] = (__bf16)b[3];
    *(bf16x8*)&out[i] = o;
}

// ---------------- prep: W [k][n] fp32 -> Wt [n][k] bf16 --------------------
__global__ __launch_bounds__(256) void wtrans(const float* __restrict__ W0, const float* __restrict__ W1,
                                              const float* __restrict__ W2, const float* __restrict__ W3,
                                              __bf16* __restrict__ T0, __bf16* __restrict__ T1,
                                              __bf16* __restrict__ T2, __bf16* __restrict__ T3) {
    const float* Ws[4] = {W0, W1, W2, W3};
    __bf16*      Ts[4] = {T0, T1, T2, T3};
    const float* W = Ws[blockIdx.z];
    __bf16*      T = Ts[blockIdx.z];
    __shared__ __bf16 t[32][33];
    int k0 = blockIdx.x * 32, n0 = blockIdx.y * 32;
    int c = threadIdx.x & 31, r = threadIdx.x >> 5;
#pragma unroll
    for (int i = 0; i < 4; ++i)
        t[r + i * 8][c] = (__bf16)W[(size_t)(k0 + r + i * 8) * DDIM + n0 + c];
    __syncthreads();
#pragma unroll
    for (int i = 0; i < 4; ++i)
        T[(size_t)(n0 + r + i * 8) * DDIM + k0 + c] = t[c][r + i * 8];
}

// ---------------- prep: bias[h][q][k] = table[rel[q][k]][h]  (bf16) --------
__global__ __launch_bounds__(256) void bias_pre(const float* __restrict__ table,
                                                const int* __restrict__ rel,
                                                __bf16* __restrict__ biasH) {
    int i = blockIdx.x * 256 + threadIdx.x;
    if (i < NHEAD * SEQ * SEQ) {
        int h = i / (SEQ * SEQ), qk = i - h * (SEQ * SEQ);
        biasH[i] = (__bf16)table[rel[qk] * NHEAD + h];
    }
}

// ---------------------------------------------------------------------------
// 256x256 8-phase GEMM: C = A[M][768] * Bt[N][768]^T + bias
// ---------------------------------------------------------------------------
template <typename OutT, int NMAT>
__global__ __launch_bounds__(512, 2) void gemm8p(const __bf16* __restrict__ A,
                                                 const __bf16* __restrict__ Bt,
                                                 const float* __restrict__ bz0,
                                                 const float* __restrict__ bz1,
                                                 const float* __restrict__ bz2,
                                                 OutT* __restrict__ Cz0,
                                                 OutT* __restrict__ Cz1,
                                                 OutT* __restrict__ Cz2,
                                                 int nbn) {
    __shared__ __bf16 As[3][256 * 64];   // 3 x 32 KiB
    __shared__ __bf16 Bs[2][256 * 64];   // 2 x 32 KiB

    const int nwg = gridDim.x, orig = blockIdx.x;
    const int qq = nwg >> 3, r8 = nwg & 7, xcd = orig & 7, lin = orig >> 3;
    const int wg = (xcd < r8 ? xcd * (qq + 1) : r8 * (qq + 1) + (xcd - r8) * qq) + lin;
    const int bm = wg / nbn, bn = wg - bm * nbn;
    const int m0 = bm * 256, n0g = bn * 256;

    const int tid = threadIdx.x, w = tid >> 6, l = tid & 63;
    const int lr = l & 15, lg = l >> 4;
    const int wrow = (w >> 2) * 128;
    const int wcol = (w & 3) * 64;

    const int srow = w * 8 + (l >> 3);
    const int scol = ((l & 7) ^ ((l >> 3) & 7)) * 8;
    const __bf16* gA = A  + (size_t)(m0 + srow) * DDIM + scol;
    const __bf16* gB = Bt + (size_t)(n0g + srow) * DDIM + scol;

#define STAGE_A(slot, h, kt)                                                      \
    do {                                                                          \
        gload16(gA + ((h) * 128 + 0) * DDIM + (kt) * 64,                          \
                &As[slot][(h) * 8192 + 0 + w * 512]);                             \
        gload16(gA + ((h) * 128 + 64) * DDIM + (kt) * 64,                         \
                &As[slot][(h) * 8192 + 4096 + w * 512]);                          \
    } while (0)
#define STAGE_B(slot, h, kt)                                                      \
    do {                                                                          \
        gload16(gB + ((h) * 128 + 0) * DDIM + (kt) * 64,                          \
                &Bs[slot][(h) * 8192 + 0 + w * 512]);                             \
        gload16(gB + ((h) * 128 + 64) * DDIM + (kt) * 64,                         \
                &Bs[slot][(h) * 8192 + 4096 + w * 512]);                          \
    } while (0)

#define AF(slot, mf, ks)                                                          \
    (*(const bf16x8*)&As[slot][(w >> 2) * 8192 + ((mf) * 16 + lr) * 64 +          \
                              ((((ks) * 4 + lg) ^ (lr & 7))) * 8])
#define BF(slot, nf, ks)                                                          \
    (*(const bf16x8*)&Bs[slot][((w & 3) >> 1) * 8192 +                            \
                              ((w & 1) * 64 + (nf) * 16 + lr) * 64 +              \
                              ((((ks) * 4 + lg) ^ (lr & 7))) * 8])

    f32x4 acc[8][4];
#pragma unroll
    for (int i = 0; i < 8; ++i)
#pragma unroll
        for (int j = 0; j < 4; ++j) acc[i][j] = (f32x4){0.f, 0.f, 0.f, 0.f};

    bf16x8 a0, a1, a2, a3;
    bf16x8 bfr00, bfr01, bfr10, bfr11, bfr20, bfr21, bfr30, bfr31;

#define DSLOAD_A(slot, mf0)                                                       \
    a0 = AF(slot, mf0, 0); a1 = AF(slot, mf0, 1);                                 \
    a2 = AF(slot, (mf0) + 1, 0); a3 = AF(slot, (mf0) + 1, 1);
#define DSLOAD_B(slot)                                                            \
    bfr00 = BF(slot, 0, 0); bfr01 = BF(slot, 0, 1);                               \
    bfr10 = BF(slot, 1, 0); bfr11 = BF(slot, 1, 1);                               \
    bfr20 = BF(slot, 2, 0); bfr21 = BF(slot, 2, 1);                               \
    bfr30 = BF(slot, 3, 0); bfr31 = BF(slot, 3, 1);
#define BARRIER_IN()                                                              \
    __builtin_amdgcn_sched_barrier(0);                                            \
    __builtin_amdgcn_s_barrier();                                                 \
    asm volatile("s_waitcnt lgkmcnt(0)" ::: "memory");                            \
    __builtin_amdgcn_sched_barrier(0);                                            \
    __builtin_amdgcn_s_setprio(1);
#define BARRIER_OUT()                                                             \
    __builtin_amdgcn_s_setprio(0);                                                \
    __builtin_amdgcn_sched_barrier(0);                                            \
    __builtin_amdgcn_s_barrier();                                                 \
    __builtin_amdgcn_sched_barrier(0);
#define MFMACL(mf0)                                                               \
    acc[mf0][0] = MFMA(a0, bfr00, acc[mf0][0]);                                   \
    acc[mf0][0] = MFMA(a1, bfr01, acc[mf0][0]);                                   \
    acc[(mf0) + 1][0] = MFMA(a2, bfr00, acc[(mf0) + 1][0]);                       \
    acc[(mf0) + 1][0] = MFMA(a3, bfr01, acc[(mf0) + 1][0]);                       \
    acc[mf0][1] = MFMA(a0, bfr10, acc[mf0][1]);                                   \
    acc[mf0][1] = MFMA(a1, bfr11, acc[mf0][1]);                                   \
    acc[(mf0) + 1][1] = MFMA(a2, bfr10, acc[(mf0) + 1][1]);                       \
    acc[(mf0) + 1][1] = MFMA(a3, bfr11, acc[(mf0) + 1][1]);                       \
    acc[mf0][2] = MFMA(a0, bfr20, acc[mf0][2]);                                   \
    acc[mf0][2] = MFMA(a1, bfr21, acc[mf0][2]);                                   \
    acc[(mf0) + 1][2] = MFMA(a2, bfr20, acc[(mf0) + 1][2]);                       \
    acc[(mf0) + 1][2] = MFMA(a3, bfr21, acc[(mf0) + 1][2]);                       \
    acc[mf0][3] = MFMA(a0, bfr30, acc[mf0][3]);                                   \
    acc[mf0][3] = MFMA(a1, bfr31, acc[mf0][3]);                                   \
    acc[(mf0) + 1][3] = MFMA(a2, bfr30, acc[(mf0) + 1][3]);                       \
    acc[(mf0) + 1][3] = MFMA(a3, bfr31, acc[(mf0) + 1][3]);

    STAGE_A(0, 0, 0); STAGE_A(0, 1, 0); STAGE_B(0, 0, 0); STAGE_B(0, 1, 0);
    STAGE_A(1, 0, 1); STAGE_A(1, 1, 1); STAGE_B(1, 0, 1); STAGE_B(1, 1, 1);
    asm volatile("s_waitcnt vmcnt(8)" ::: "memory");
    __builtin_amdgcn_s_barrier();
    __builtin_amdgcn_sched_barrier(0);

#pragma unroll
    for (int i = 0; i < 6; ++i) {
        const int s0 = (2 * i) % 3, s1 = (2 * i + 1) % 3, s2 = (2 * i + 2) % 3;
        // ---- phase 0
        DSLOAD_A(s0, 0); DSLOAD_B(0);
        if (i < 5) STAGE_A(s2, 0, 2 * i + 2);
        BARRIER_IN(); MFMACL(0); BARRIER_OUT();
        // ---- phase 1
        DSLOAD_A(s0, 2);
        if (i < 5) STAGE_A(s2, 1, 2 * i + 2);
        BARRIER_IN(); MFMACL(2); BARRIER_OUT();
        // ---- phase 2
        DSLOAD_A(s0, 4);
        if (i < 5) STAGE_B(0, 0, 2 * i + 2);
        BARRIER_IN(); MFMACL(4); BARRIER_OUT();
        // ---- phase 3
        DSLOAD_A(s0, 6);
        if (i < 5) {
            STAGE_B(0, 1, 2 * i + 2);
            asm volatile("s_waitcnt vmcnt(8)" ::: "memory");
        } else {
            asm volatile("s_waitcnt vmcnt(0)" ::: "memory");
        }
        BARRIER_IN(); MFMACL(6); BARRIER_OUT();
        // ---- phase 4
        DSLOAD_A(s1, 0); DSLOAD_B(1);
        if (i < 5) STAGE_A(s0, 0, 2 * i + 3);
        BARRIER_IN(); MFMACL(0); BARRIER_OUT();
        // ---- phase 5
        DSLOAD_A(s1, 2);
        if (i < 5) STAGE_A(s0, 1, 2 * i + 3);
        BARRIER_IN(); MFMACL(2); BARRIER_OUT();
        // ---- phase 6
        DSLOAD_A(s1, 4);
        if (i < 5) STAGE_B(1, 0, 2 * i + 3);
        BARRIER_IN(); MFMACL(4); BARRIER_OUT();
        // ---- phase 7
        DSLOAD_A(s1, 6);
        if (i < 5) {
            STAGE_B(1, 1, 2 * i + 3);
            asm volatile("s_waitcnt vmcnt(8)" ::: "memory");
        }
        BARRIER_IN(); MFMACL(6); BARRIER_OUT();
    }

    const int mat = (NMAT == 1) ? 0 : (n0g / DDIM);
    const int colbase = n0g - mat * DDIM + wcol;
    const float* bz = (mat == 0) ? bz0 : (mat == 1 ? bz1 : bz2);
    OutT* Cc = (mat == 0) ? Cz0 : (mat == 1 ? Cz1 : Cz2);
#pragma unroll
    for (int nf = 0; nf < 4; ++nf) {
        const int col = colbase + nf * 16 + lr;
        const float bb = bz[col];
#pragma unroll
        for (int mf = 0; mf < 8; ++mf) {
            const int row = m0 + wrow + mf * 16 + lg * 4;
#pragma unroll
            for (int r2 = 0; r2 < 4; ++r2)
                Cc[(size_t)(row + r2) * DDIM + col] = (OutT)(acc[mf][nf][r2] + bb);
        }
    }
#undef STAGE_A
#undef STAGE_B
#undef AF
#undef BF
#undef DSLOAD_A
#undef DSLOAD_B
#undef BARRIER_IN
#undef BARRIER_OUT
#undef MFMACL
}

// ---------------- attn chunk: QK^T tiles T0..T0+NTC-1, PV kt KT0..+NKT-1 ---
template <int T0, int NTC, int KT0, int NKT, bool REZERO>
static __device__ __forceinline__ void attn_chunk(
    const __bf16* Ksm, const __bf16* Vts, __bf16* Pw, const __bf16* bh,
    int qrow, int lr, int lg, bf16x8 bq0, bf16x8 bq1,
    float& m_run, float& s_run, f32x4* oa) {
    f32x4 sc[NTC];
    __builtin_amdgcn_s_setprio(1);
#pragma unroll
    for (int tt = 0; tt < NTC; ++tt) {
        const int t = T0 + tt;
        bf16x8 kf0 = *(const bf16x8*)&Ksm[(t * 16 + lr) * KSTR + lg * 8];
        bf16x8 kf1 = *(const bf16x8*)&Ksm[(t * 16 + lr) * KSTR + 32 + lg * 8];
        f32x4 a = {0.f, 0.f, 0.f, 0.f};
        a = MFMA(kf0, bq0, a);
        a = MFMA(kf1, bq1, a);
        sc[tt] = a;
    }
    __builtin_amdgcn_s_setprio(0);
    float mc = -1e30f;
#pragma unroll
    for (int tt = 0; tt < NTC; ++tt) {
        const int t = T0 + tt;
        const bool val4 = (t < 12) || (lg == 0);
        float bb[4] = {0.f, 0.f, 0.f, 0.f};
        if (val4) {
            bf16x4 b4 = *(const bf16x4*)&bh[(size_t)qrow * SEQ + t * 16 + lg * 4];
#pragma unroll
            for (int r = 0; r < 4; ++r) bb[r] = (float)b4[r];
        }
#pragma unroll
        for (int r = 0; r < 4; ++r) {
            float v = val4 ? (sc[tt][r] * 0.125f + bb[r]) : -1e30f;
            sc[tt][r] = v;
            mc = fmaxf(mc, v);
        }
    }
    mc = fmaxf(mc, __shfl_xor(mc, 16));
    mc = fmaxf(mc, __shfl_xor(mc, 32));
    const float mnew = fmaxf(m_run, mc);
    const float fsc = __expf(m_run - mnew);
    m_run = mnew;
    s_run *= fsc;
#pragma unroll
    for (int i = 0; i < 4; ++i)
#pragma unroll
        for (int r = 0; r < 4; ++r) oa[i][r] *= fsc;
    float ps = 0.f;
#pragma unroll
    for (int tt = 0; tt < NTC; ++tt) {
        bf16x4 pk;
#pragma unroll
        for (int r = 0; r < 4; ++r) {
            float p = __expf(sc[tt][r] - m_run);
            ps += p;
            pk[r] = (__bf16)p;
        }
        *(bf16x4*)&Pw[lr * PSTR + tt * 16 + lg * 4] = pk;   // chunk-relative cols
    }
    ps += __shfl_xor(ps, 16);
    ps += __shfl_xor(ps, 32);
    s_run += ps;
    if (REZERO) {   // zero rel cols 16..31 (kk pad) before PV reads them
        bf16x4 z4 = {(__bf16)0.f, (__bf16)0.f, (__bf16)0.f, (__bf16)0.f};
        *(bf16x4*)&Pw[lr * PSTR + 16 + lg * 4] = z4;
    }
    __builtin_amdgcn_s_setprio(1);
#pragma unroll
    for (int ktl = 0; ktl < NKT; ++ktl) {
        bf16x8 pf = *(const bf16x8*)&Pw[lr * PSTR + ktl * 32 + lg * 8];
#pragma unroll
        for (int nt = 0; nt < 4; ++nt) {
            bf16x8 vf = *(const bf16x8*)&Vts[(nt * 16 + lr) * VSTR + (KT0 + ktl) * 32 + lg * 8];
            oa[nt] = MFMA(vf, pf, oa[nt]);
        }
    }
    __builtin_amdgcn_s_setprio(0);
}

// ---------------- fused attention: 75 KB LDS, 2 blocks/CU, 128-reg budget --
// (512, 2): empirically VGPR cap = 128 for 8-wave blocks; chunked live set
// (~80-90 regs) fits without spill. (512,4) capped at 64 and spilled 450 MB.
__global__ __launch_bounds__(512, 2) void attn_kernel(const __bf16* __restrict__ Qg,
                                                      const __bf16* __restrict__ Kg,
                                                      const __bf16* __restrict__ Vg,
                                                      const __bf16* __restrict__ biasH,
                                                      __bf16* __restrict__ Og) {
    __shared__ __bf16 Ksm[208 * KSTR];      // 28.3 KB
    __shared__ __bf16 Vts[64 * VSTR];       // 29.7 KB
    __shared__ __bf16 Psm[8 * 16 * PSTR];   // 17.4 KB  (per-wave [16][68], chunk-relative)

    const int b = blockIdx.x, h = blockIdx.y;
    const int tid = threadIdx.x, w = tid >> 6, l = tid & 63;
    const int lr = l & 15, lg = l >> 4;
    const size_t base = (size_t)(b * SEQ) * DDIM + h * 64;
    const __bf16* Kb = Kg + base;
    const __bf16* Vb = Vg + base;
    const __bf16* Qb = Qg + base;
    const __bf16* bh = biasH + (size_t)h * (SEQ * SEQ);

    // stage K rows (16B chunks), cols 0..63
    for (int c = tid; c < SEQ * 8; c += 512) {
        int kk = c >> 3, d8 = (c & 7) << 3;
        *(bf16x8*)&Ksm[kk * KSTR + d8] = *(const bf16x8*)&Kb[(size_t)kk * DDIM + d8];
    }
    // zero K pad rows 196..207
    for (int c = tid; c < 12 * 8; c += 512) {
        int kk = SEQ + (c >> 3), d8 = (c & 7) << 3;
        *(uint4*)&Ksm[kk * KSTR + d8] = make_uint4(0u, 0u, 0u, 0u);
    }
    // stage V transposed
    for (int c = tid; c < SEQ * 8; c += 512) {
        int kk = c >> 3, d8 = (c & 7) << 3;
        bf16x8 vv = *(const bf16x8*)&Vb[(size_t)kk * DDIM + d8];
#pragma unroll
        for (int j = 0; j < 8; ++j) Vts[(d8 + j) * VSTR + kk] = vv[j];
    }
    // zero Vt cols 196..223
    for (int c = tid; c < 64 * 28; c += 512)
        Vts[(c / 28) * VSTR + SEQ + (c % 28)] = (__bf16)0.f;
    __syncthreads();

    __bf16* Pw = &Psm[w * 16 * PSTR];

    for (int qt = w; qt < 13; qt += 8) {
        const int q0 = qt * 16;
        const int q = q0 + lr;
        const int qrow = min(q, SEQ - 1);
        bf16x8 bq0 = *(const bf16x8*)&Qb[(size_t)qrow * DDIM + lg * 8];
        bf16x8 bq1 = *(const bf16x8*)&Qb[(size_t)qrow * DDIM + 32 + lg * 8];

        float m_run = -1e30f, s_run = 0.f;
        f32x4 oa[4];
#pragma unroll
        for (int i = 0; i < 4; ++i) oa[i] = (f32x4){0.f, 0.f, 0.f, 0.f};

        attn_chunk<0, 4, 0, 2, false>(Ksm, Vts, Pw, bh, qrow, lr, lg, bq0, bq1, m_run, s_run, oa);
        attn_chunk<4, 4, 2, 2, false>(Ksm, Vts, Pw, bh, qrow, lr, lg, bq0, bq1, m_run, s_run, oa);
        attn_chunk<8, 4, 4, 2, false>(Ksm, Vts, Pw, bh, qrow, lr, lg, bq0, bq1, m_run, s_run, oa);
        attn_chunk<12, 1, 6, 1, true>(Ksm, Vts, Pw, bh, qrow, lr, lg, bq0, bq1, m_run, s_run, oa);

        const float inv = 1.f / s_run;
        if (q < SEQ) {
#pragma unroll
            for (int nt = 0; nt < 4; ++nt) {
                bf16x4 ok;
#pragma unroll
                for (int r = 0; r < 4; ++r) ok[r] = (__bf16)(oa[nt][r] * inv);
                *(bf16x4*)&Og[(size_t)(b * SEQ + q) * DDIM + h * 64 + nt * 16 + lg * 4] = ok;
            }
        }
    }
}

// ---------------------------------------------------------------------------
extern "C" void kernel_launch(void* const* d_in, const int* in_sizes, int n_in,
                              void* d_out, int out_size, void* d_ws, size_t ws_size,
                              hipStream_t stream) {
    const float* x     = (const float*)d_in[0];
    const float* Wq    = (const float*)d_in[1];
    const float* bq    = (const float*)d_in[2];
    const float* Wk    = (const float*)d_in[3];
    const float* bk    = (const float*)d_in[4];
    const float* Wv    = (const float*)d_in[5];
    const float* bv    = (const float*)d_in[6];
    const float* Wo    = (const float*)d_in[7];
    const float* bo    = (const float*)d_in[8];
    const float* table = (const float*)d_in[9];
    const int*   rel   = (const int*)d_in[10];
    float* out = (float*)d_out;

    char* ws = (char*)d_ws;
    auto alloc = [&](size_t bytes) {
        char* p = ws;
        ws += (bytes + 255) & ~(size_t)255;
        return p;
    };
    const size_t mat = (size_t)MROWS * DDIM * sizeof(__bf16);
    __bf16* xb    = (__bf16*)alloc(mat);
    __bf16* Tqkv  = (__bf16*)alloc((size_t)3 * DDIM * DDIM * 2);
    __bf16* To    = (__bf16*)alloc((size_t)DDIM * DDIM * 2);
    __bf16* Qb    = (__bf16*)alloc(mat);
    __bf16* Kb    = (__bf16*)alloc(mat);
    __bf16* Vb    = (__bf16*)alloc(mat);
    __bf16* AO    = (__bf16*)alloc(mat);
    __bf16* biasH = (__bf16*)alloc((size_t)NHEAD * SEQ * SEQ * 2);

    f2b<<<dim3(4704), 256, 0, stream>>>(x, xb);
    wtrans<<<dim3(24, 24, 4), 256, 0, stream>>>(Wq, Wk, Wv, Wo,
                                                Tqkv, Tqkv + (size_t)DDIM * DDIM,
                                                Tqkv + (size_t)2 * DDIM * DDIM, To);
    bias_pre<<<dim3(1801), 256, 0, stream>>>(table, rel, biasH);

    gemm8p<__bf16, 3><<<dim3(441), 512, 0, stream>>>(xb, Tqkv, bq, bk, bv,
                                                     Qb, Kb, Vb, 9);
    attn_kernel<<<dim3(64, 12), 512, 0, stream>>>(Qb, Kb, Vb, biasH, AO);
    gemm8p<float, 1><<<dim3(147), 512, 0, stream>>>(AO, To, bo, bo, bo,
                                                    out, out, out, 3);
}

// Round 8
// 172.010 us; speedup vs baseline: 1.5460x; 1.0335x over previous
//
#include <hip/hip_runtime.h>
#include <hip/hip_bf16.h>

// ---------------------------------------------------------------------------
// MultiHeadSelfAttention (Swin rel-pos bias), B=64 S=196 D=768 H=12 pd=64
// f2b ; wtrans(stacked) ; bias_pre(bf16) ; gemm8p QKV (256^2 8-phase) ;
// attn (S^T, direct-K, rotating-P, 40KB LDS, 2 blocks/CU) ; gemm8p O-proj
// ---------------------------------------------------------------------------

typedef __bf16 bf16x8 __attribute__((ext_vector_type(8)));
typedef __bf16 bf16x4 __attribute__((ext_vector_type(4)));
typedef float  f32x4  __attribute__((ext_vector_type(4)));

#define MROWS 12544
#define DDIM  768
#define NHEAD 12
#define SEQ   196
#define VSTR  232        // Vts row stride (2-way max on vf reads)
#define PSTR  40         // rotating P row stride: [16 q][32 kk + 8 pad]

static __device__ __forceinline__ f32x4 MFMA(bf16x8 a, bf16x8 b, f32x4 c) {
    return __builtin_amdgcn_mfma_f32_16x16x32_bf16(a, b, c, 0, 0, 0);
}

static __device__ __forceinline__ void gload16(const __bf16* g, __bf16* l) {
    __builtin_amdgcn_global_load_lds(
        (const __attribute__((address_space(1))) void*)(g),
        (__attribute__((address_space(3))) void*)(l),
        16, 0, 0);
}

// ---------------- prep: fp32 -> bf16 ---------------------------------------
__global__ __launch_bounds__(256) void f2b(const float* __restrict__ in,
                                           __bf16* __restrict__ out) {
    size_t i = ((size_t)blockIdx.x * 256 + threadIdx.x) * 8;
    f32x4 a = *(const f32x4*)&in[i];
    f32x4 b = *(const f32x4*)&in[i + 4];
    bf16x8 o;
    o[0] = (__bf16)a[0]; o[1] = (__bf16)a[1]; o[2] = (__bf16)a[2]; o[3] = (__bf16)a[3];
    o[4] = (__bf16)b[0]; o[5] = (__bf16)b[1]; o[6] = (__bf16)b[2]; o[7] = (__bf16)b[3];
    *(bf16x8*)&out[i] = o;
}

// ---------------- prep: W [k][n] fp32 -> Wt [n][k] bf16 --------------------
__global__ __launch_bounds__(256) void wtrans(const float* __restrict__ W0, const float* __restrict__ W1,
                                              const float* __restrict__ W2, const float* __restrict__ W3,
                                              __bf16* __restrict__ T0, __bf16* __restrict__ T1,
                                              __bf16* __restrict__ T2, __bf16* __restrict__ T3) {
    const float* Ws[4] = {W0, W1, W2, W3};
    __bf16*      Ts[4] = {T0, T1, T2, T3};
    const float* W = Ws[blockIdx.z];
    __bf16*      T = Ts[blockIdx.z];
    __shared__ __bf16 t[32][33];
    int k0 = blockIdx.x * 32, n0 = blockIdx.y * 32;
    int c = threadIdx.x & 31, r = threadIdx.x >> 5;
#pragma unroll
    for (int i = 0; i < 4; ++i)
        t[r + i * 8][c] = (__bf16)W[(size_t)(k0 + r + i * 8) * DDIM + n0 + c];
    __syncthreads();
#pragma unroll
    for (int i = 0; i < 4; ++i)
        T[(size_t)(n0 + r + i * 8) * DDIM + k0 + c] = t[c][r + i * 8];
}

// ---------------- prep: bias[h][q][k] = table[rel[q][k]][h]  (bf16) --------
__global__ __launch_bounds__(256) void bias_pre(const float* __restrict__ table,
                                                const int* __restrict__ rel,
                                                __bf16* __restrict__ biasH) {
    int i = blockIdx.x * 256 + threadIdx.x;
    if (i < NHEAD * SEQ * SEQ) {
        int h = i / (SEQ * SEQ), qk = i - h * (SEQ * SEQ);
        biasH[i] = (__bf16)table[rel[qk] * NHEAD + h];
    }
}

// ---------------------------------------------------------------------------
// 256x256 8-phase GEMM: C = A[M][768] * Bt[N][768]^T + bias   (unchanged)
// ---------------------------------------------------------------------------
template <typename OutT, int NMAT>
__global__ __launch_bounds__(512, 2) void gemm8p(const __bf16* __restrict__ A,
                                                 const __bf16* __restrict__ Bt,
                                                 const float* __restrict__ bz0,
                                                 const float* __restrict__ bz1,
                                                 const float* __restrict__ bz2,
                                                 OutT* __restrict__ Cz0,
                                                 OutT* __restrict__ Cz1,
                                                 OutT* __restrict__ Cz2,
                                                 int nbn) {
    __shared__ __bf16 As[3][256 * 64];   // 3 x 32 KiB
    __shared__ __bf16 Bs[2][256 * 64];   // 2 x 32 KiB

    const int nwg = gridDim.x, orig = blockIdx.x;
    const int qq = nwg >> 3, r8 = nwg & 7, xcd = orig & 7, lin = orig >> 3;
    const int wg = (xcd < r8 ? xcd * (qq + 1) : r8 * (qq + 1) + (xcd - r8) * qq) + lin;
    const int bm = wg / nbn, bn = wg - bm * nbn;
    const int m0 = bm * 256, n0g = bn * 256;

    const int tid = threadIdx.x, w = tid >> 6, l = tid & 63;
    const int lr = l & 15, lg = l >> 4;
    const int wrow = (w >> 2) * 128;
    const int wcol = (w & 3) * 64;

    const int srow = w * 8 + (l >> 3);
    const int scol = ((l & 7) ^ ((l >> 3) & 7)) * 8;
    const __bf16* gA = A  + (size_t)(m0 + srow) * DDIM + scol;
    const __bf16* gB = Bt + (size_t)(n0g + srow) * DDIM + scol;

#define STAGE_A(slot, h, kt)                                                      \
    do {                                                                          \
        gload16(gA + ((h) * 128 + 0) * DDIM + (kt) * 64,                          \
                &As[slot][(h) * 8192 + 0 + w * 512]);                             \
        gload16(gA + ((h) * 128 + 64) * DDIM + (kt) * 64,                         \
                &As[slot][(h) * 8192 + 4096 + w * 512]);                          \
    } while (0)
#define STAGE_B(slot, h, kt)                                                      \
    do {                                                                          \
        gload16(gB + ((h) * 128 + 0) * DDIM + (kt) * 64,                          \
                &Bs[slot][(h) * 8192 + 0 + w * 512]);                             \
        gload16(gB + ((h) * 128 + 64) * DDIM + (kt) * 64,                         \
                &Bs[slot][(h) * 8192 + 4096 + w * 512]);                          \
    } while (0)

#define AF(slot, mf, ks)                                                          \
    (*(const bf16x8*)&As[slot][(w >> 2) * 8192 + ((mf) * 16 + lr) * 64 +          \
                              ((((ks) * 4 + lg) ^ (lr & 7))) * 8])
#define BF(slot, nf, ks)                                                          \
    (*(const bf16x8*)&Bs[slot][((w & 3) >> 1) * 8192 +                            \
                              ((w & 1) * 64 + (nf) * 16 + lr) * 64 +              \
                              ((((ks) * 4 + lg) ^ (lr & 7))) * 8])

    f32x4 acc[8][4];
#pragma unroll
    for (int i = 0; i < 8; ++i)
#pragma unroll
        for (int j = 0; j < 4; ++j) acc[i][j] = (f32x4){0.f, 0.f, 0.f, 0.f};

    bf16x8 a0, a1, a2, a3;
    bf16x8 bfr00, bfr01, bfr10, bfr11, bfr20, bfr21, bfr30, bfr31;

#define DSLOAD_A(slot, mf0)                                                       \
    a0 = AF(slot, mf0, 0); a1 = AF(slot, mf0, 1);                                 \
    a2 = AF(slot, (mf0) + 1, 0); a3 = AF(slot, (mf0) + 1, 1);
#define DSLOAD_B(slot)                                                            \
    bfr00 = BF(slot, 0, 0); bfr01 = BF(slot, 0, 1);                               \
    bfr10 = BF(slot, 1, 0); bfr11 = BF(slot, 1, 1);                               \
    bfr20 = BF(slot, 2, 0); bfr21 = BF(slot, 2, 1);                               \
    bfr30 = BF(slot, 3, 0); bfr31 = BF(slot, 3, 1);
#define BARRIER_IN()                                                              \
    __builtin_amdgcn_sched_barrier(0);                                            \
    __builtin_amdgcn_s_barrier();                                                 \
    asm volatile("s_waitcnt lgkmcnt(0)" ::: "memory");                            \
    __builtin_amdgcn_sched_barrier(0);                                            \
    __builtin_amdgcn_s_setprio(1);
#define BARRIER_OUT()                                                             \
    __builtin_amdgcn_s_setprio(0);                                                \
    __builtin_amdgcn_sched_barrier(0);                                            \
    __builtin_amdgcn_s_barrier();                                                 \
    __builtin_amdgcn_sched_barrier(0);
#define MFMACL(mf0)                                                               \
    acc[mf0][0] = MFMA(a0, bfr00, acc[mf0][0]);                                   \
    acc[mf0][0] = MFMA(a1, bfr01, acc[mf0][0]);                                   \
    acc[(mf0) + 1][0] = MFMA(a2, bfr00, acc[(mf0) + 1][0]);                       \
    acc[(mf0) + 1][0] = MFMA(a3, bfr01, acc[(mf0) + 1][0]);                       \
    acc[mf0][1] = MFMA(a0, bfr10, acc[mf0][1]);                                   \
    acc[mf0][1] = MFMA(a1, bfr11, acc[mf0][1]);                                   \
    acc[(mf0) + 1][1] = MFMA(a2, bfr10, acc[(mf0) + 1][1]);                       \
    acc[(mf0) + 1][1] = MFMA(a3, bfr11, acc[(mf0) + 1][1]);                       \
    acc[mf0][2] = MFMA(a0, bfr20, acc[mf0][2]);                                   \
    acc[mf0][2] = MFMA(a1, bfr21, acc[mf0][2]);                                   \
    acc[(mf0) + 1][2] = MFMA(a2, bfr20, acc[(mf0) + 1][2]);                       \
    acc[(mf0) + 1][2] = MFMA(a3, bfr21, acc[(mf0) + 1][2]);                       \
    acc[mf0][3] = MFMA(a0, bfr30, acc[mf0][3]);                                   \
    acc[mf0][3] = MFMA(a1, bfr31, acc[mf0][3]);                                   \
    acc[(mf0) + 1][3] = MFMA(a2, bfr30, acc[(mf0) + 1][3]);                       \
    acc[(mf0) + 1][3] = MFMA(a3, bfr31, acc[(mf0) + 1][3]);

    STAGE_A(0, 0, 0); STAGE_A(0, 1, 0); STAGE_B(0, 0, 0); STAGE_B(0, 1, 0);
    STAGE_A(1, 0, 1); STAGE_A(1, 1, 1); STAGE_B(1, 0, 1); STAGE_B(1, 1, 1);
    asm volatile("s_waitcnt vmcnt(8)" ::: "memory");
    __builtin_amdgcn_s_barrier();
    __builtin_amdgcn_sched_barrier(0);

#pragma unroll
    for (int i = 0; i < 6; ++i) {
        const int s0 = (2 * i) % 3, s1 = (2 * i + 1) % 3, s2 = (2 * i + 2) % 3;
        // ---- phase 0
        DSLOAD_A(s0, 0); DSLOAD_B(0);
        if (i < 5) STAGE_A(s2, 0, 2 * i + 2);
        BARRIER_IN(); MFMACL(0); BARRIER_OUT();
        // ---- phase 1
        DSLOAD_A(s0, 2);
        if (i < 5) STAGE_A(s2, 1, 2 * i + 2);
        BARRIER_IN(); MFMACL(2); BARRIER_OUT();
        // ---- phase 2
        DSLOAD_A(s0, 4);
        if (i < 5) STAGE_B(0, 0, 2 * i + 2);
        BARRIER_IN(); MFMACL(4); BARRIER_OUT();
        // ---- phase 3
        DSLOAD_A(s0, 6);
        if (i < 5) {
            STAGE_B(0, 1, 2 * i + 2);
            asm volatile("s_waitcnt vmcnt(8)" ::: "memory");
        } else {
            asm volatile("s_waitcnt vmcnt(0)" ::: "memory");
        }
        BARRIER_IN(); MFMACL(6); BARRIER_OUT();
        // ---- phase 4
        DSLOAD_A(s1, 0); DSLOAD_B(1);
        if (i < 5) STAGE_A(s0, 0, 2 * i + 3);
        BARRIER_IN(); MFMACL(0); BARRIER_OUT();
        // ---- phase 5
        DSLOAD_A(s1, 2);
        if (i < 5) STAGE_A(s0, 1, 2 * i + 3);
        BARRIER_IN(); MFMACL(2); BARRIER_OUT();
        // ---- phase 6
        DSLOAD_A(s1, 4);
        if (i < 5) STAGE_B(1, 0, 2 * i + 3);
        BARRIER_IN(); MFMACL(4); BARRIER_OUT();
        // ---- phase 7
        DSLOAD_A(s1, 6);
        if (i < 5) {
            STAGE_B(1, 1, 2 * i + 3);
            asm volatile("s_waitcnt vmcnt(8)" ::: "memory");
        }
        BARRIER_IN(); MFMACL(6); BARRIER_OUT();
    }

    const int mat = (NMAT == 1) ? 0 : (n0g / DDIM);
    const int colbase = n0g - mat * DDIM + wcol;
    const float* bz = (mat == 0) ? bz0 : (mat == 1 ? bz1 : bz2);
    OutT* Cc = (mat == 0) ? Cz0 : (mat == 1 ? Cz1 : Cz2);
#pragma unroll
    for (int nf = 0; nf < 4; ++nf) {
        const int col = colbase + nf * 16 + lr;
        const float bb = bz[col];
#pragma unroll
        for (int mf = 0; mf < 8; ++mf) {
            const int row = m0 + wrow + mf * 16 + lg * 4;
#pragma unroll
            for (int r2 = 0; r2 < 4; ++r2)
                Cc[(size_t)(row + r2) * DDIM + col] = (OutT)(acc[mf][nf][r2] + bb);
        }
    }
#undef STAGE_A
#undef STAGE_B
#undef AF
#undef BF
#undef DSLOAD_A
#undef DSLOAD_B
#undef BARRIER_IN
#undef BARRIER_OUT
#undef MFMACL
}

// ---------------- attn chunk: direct-K QK^T + rotating-P PV ----------------
// tiles T0..T0+NTC-1; PV kt = KT0..KT0+NKT-1 (kt covers tiles 2kt,2kt+1 global)
template <int T0, int NTC, int KT0, int NKT>
static __device__ __forceinline__ void attn_chunk(
    const __bf16* __restrict__ Kb, const __bf16* Vts, __bf16* Pw,
    const __bf16* __restrict__ bh,
    int qrow, int lr, int lg, bf16x8 bq0, bf16x8 bq1,
    float& m_run, float& s_run, f32x4 (&oa)[4]) {
    f32x4 sc[NTC];
    __builtin_amdgcn_s_setprio(1);
#pragma unroll
    for (int tt = 0; tt < NTC; ++tt) {
        const int t = T0 + tt;
        const int krow = min(t * 16 + lr, SEQ - 1);   // clamp: no global OOB
        bf16x8 kf0 = *(const bf16x8*)&Kb[(size_t)krow * DDIM + lg * 8];
        bf16x8 kf1 = *(const bf16x8*)&Kb[(size_t)krow * DDIM + 32 + lg * 8];
        f32x4 a = {0.f, 0.f, 0.f, 0.f};
        a = MFMA(kf0, bq0, a);
        a = MFMA(kf1, bq1, a);
        sc[tt] = a;
    }
    __builtin_amdgcn_s_setprio(0);
    float mc = -1e30f;
#pragma unroll
    for (int tt = 0; tt < NTC; ++tt) {
        const int t = T0 + tt;
        const bool val4 = (t < 12) || (lg == 0);      // kk quad fully < 196
        float bb[4] = {0.f, 0.f, 0.f, 0.f};
        if (val4) {
            bf16x4 b4 = *(const bf16x4*)&bh[(size_t)qrow * SEQ + t * 16 + lg * 4];
#pragma unroll
            for (int r = 0; r < 4; ++r) bb[r] = (float)b4[r];
        }
#pragma unroll
        for (int r = 0; r < 4; ++r) {
            float v = val4 ? (sc[tt][r] * 0.125f + bb[r]) : -1e30f;
            sc[tt][r] = v;
            mc = fmaxf(mc, v);
        }
    }
    mc = fmaxf(mc, __shfl_xor(mc, 16));
    mc = fmaxf(mc, __shfl_xor(mc, 32));
    const float mnew = fmaxf(m_run, mc);
    const float fsc = __expf(m_run - mnew);
    m_run = mnew;
    s_run *= fsc;
#pragma unroll
    for (int i = 0; i < 4; ++i)
#pragma unroll
        for (int r = 0; r < 4; ++r) oa[i][r] *= fsc;
    float ps = 0.f;
#pragma unroll
    for (int tt = 0; tt < NTC; ++tt)
#pragma unroll
        for (int r = 0; r < 4; ++r) {
            float p = __expf(sc[tt][r] - m_run);
            ps += p;
            sc[tt][r] = p;                            // keep exp'd P in regs
        }
    ps += __shfl_xor(ps, 16);
    ps += __shfl_xor(ps, 32);
    s_run += ps;

    // PV with rotating per-wave P buffer [16][PSTR]: write one kt, read, MFMA
    __builtin_amdgcn_s_setprio(1);
#pragma unroll
    for (int ktl = 0; ktl < NKT; ++ktl) {
        const int tt0 = 2 * ktl, tt1 = 2 * ktl + 1;
        bf16x4 pk0, pk1;
#pragma unroll
        for (int r = 0; r < 4; ++r) pk0[r] = (__bf16)sc[tt0][r];
        if (tt1 < NTC) {
#pragma unroll
            for (int r = 0; r < 4; ++r) pk1[r] = (__bf16)sc[tt1][r];
        } else {
#pragma unroll
            for (int r = 0; r < 4; ++r) pk1[r] = (__bf16)0.f;
        }
        *(bf16x4*)&Pw[lr * PSTR + lg * 4]      = pk0;   // tile 2kt   -> cols 0..15
        *(bf16x4*)&Pw[lr * PSTR + 16 + lg * 4] = pk1;   // tile 2kt+1 -> cols 16..31
        bf16x8 pf = *(const bf16x8*)&Pw[lr * PSTR + lg * 8];
#pragma unroll
        for (int nt = 0; nt < 4; ++nt) {
            bf16x8 vf = *(const bf16x8*)&Vts[(nt * 16 + lr) * VSTR + (KT0 + ktl) * 32 + lg * 8];
            oa[nt] = MFMA(vf, pf, oa[nt]);
        }
    }
    __builtin_amdgcn_s_setprio(0);
}

// ---------------- fused attention: 40 KB LDS, direct-K, 2 blocks/CU --------
__global__ __launch_bounds__(512, 2) void attn_kernel(const __bf16* __restrict__ Qg,
                                                      const __bf16* __restrict__ Kg,
                                                      const __bf16* __restrict__ Vg,
                                                      const __bf16* __restrict__ biasH,
                                                      __bf16* __restrict__ Og) {
    __shared__ __bf16 Vts[64 * VSTR];       // 29.7 KB  V^T: [d][kk]
    __shared__ __bf16 Psm[8 * 16 * PSTR];   // 10.0 KB  rotating P per wave

    const int b = blockIdx.x, h = blockIdx.y;
    const int tid = threadIdx.x, w = tid >> 6, l = tid & 63;
    const int lr = l & 15, lg = l >> 4;
    const size_t base = (size_t)(b * SEQ) * DDIM + h * 64;
    const __bf16* Kb = Kg + base;
    const __bf16* Vb = Vg + base;
    const __bf16* Qb = Qg + base;
    const __bf16* bh = biasH + (size_t)h * (SEQ * SEQ);

    // stage V transposed
    for (int c = tid; c < SEQ * 8; c += 512) {
        int kk = c >> 3, d8 = (c & 7) << 3;
        bf16x8 vv = *(const bf16x8*)&Vb[(size_t)kk * DDIM + d8];
#pragma unroll
        for (int j = 0; j < 8; ++j) Vts[(d8 + j) * VSTR + kk] = vv[j];
    }
    // zero Vt cols 196..223 (defensive: multiplied by zero-P anyway)
    for (int c = tid; c < 64 * 28; c += 512)
        Vts[(c / 28) * VSTR + SEQ + (c % 28)] = (__bf16)0.f;
    __syncthreads();

    __bf16* Pw = &Psm[w * 16 * PSTR];

    for (int qt = w; qt < 13; qt += 8) {
        const int q0 = qt * 16;
        const int q = q0 + lr;
        const int qrow = min(q, SEQ - 1);
        bf16x8 bq0 = *(const bf16x8*)&Qb[(size_t)qrow * DDIM + lg * 8];
        bf16x8 bq1 = *(const bf16x8*)&Qb[(size_t)qrow * DDIM + 32 + lg * 8];

        float m_run = -1e30f, s_run = 0.f;
        f32x4 oa[4];
#pragma unroll
        for (int i = 0; i < 4; ++i) oa[i] = (f32x4){0.f, 0.f, 0.f, 0.f};

        attn_chunk<0, 8, 0, 4>(Kb, Vts, Pw, bh, qrow, lr, lg, bq0, bq1, m_run, s_run, oa);
        attn_chunk<8, 5, 4, 3>(Kb, Vts, Pw, bh, qrow, lr, lg, bq0, bq1, m_run, s_run, oa);

        const float inv = 1.f / s_run;
        if (q < SEQ) {
#pragma unroll
            for (int nt = 0; nt < 4; ++nt) {
                bf16x4 ok;
#pragma unroll
                for (int r = 0; r < 4; ++r) ok[r] = (__bf16)(oa[nt][r] * inv);
                *(bf16x4*)&Og[(size_t)(b * SEQ + q) * DDIM + h * 64 + nt * 16 + lg * 4] = ok;
            }
        }
    }
}

// ---------------------------------------------------------------------------
extern "C" void kernel_launch(void* const* d_in, const int* in_sizes, int n_in,
                              void* d_out, int out_size, void* d_ws, size_t ws_size,
                              hipStream_t stream) {
    const float* x     = (const float*)d_in[0];
    const float* Wq    = (const float*)d_in[1];
    const float* bq    = (const float*)d_in[2];
    const float* Wk    = (const float*)d_in[3];
    const float* bk    = (const float*)d_in[4];
    const float* Wv    = (const float*)d_in[5];
    const float* bv    = (const float*)d_in[6];
    const float* Wo    = (const float*)d_in[7];
    const float* bo    = (const float*)d_in[8];
    const float* table = (const float*)d_in[9];
    const int*   rel   = (const int*)d_in[10];
    float* out = (float*)d_out;

    char* ws = (char*)d_ws;
    auto alloc = [&](size_t bytes) {
        char* p = ws;
        ws += (bytes + 255) & ~(size_t)255;
        return p;
    };
    const size_t mat = (size_t)MROWS * DDIM * sizeof(__bf16);
    __bf16* xb    = (__bf16*)alloc(mat);
    __bf16* Tqkv  = (__bf16*)alloc((size_t)3 * DDIM * DDIM * 2);
    __bf16* To    = (__bf16*)alloc((size_t)DDIM * DDIM * 2);
    __bf16* Qb    = (__bf16*)alloc(mat);
    __bf16* Kb    = (__bf16*)alloc(mat);
    __bf16* Vb    = (__bf16*)alloc(mat);
    __bf16* AO    = (__bf16*)alloc(mat);
    __bf16* biasH = (__bf16*)alloc((size_t)NHEAD * SEQ * SEQ * 2);

    f2b<<<dim3(4704), 256, 0, stream>>>(x, xb);
    wtrans<<<dim3(24, 24, 4), 256, 0, stream>>>(Wq, Wk, Wv, Wo,
                                                Tqkv, Tqkv + (size_t)DDIM * DDIM,
                                                Tqkv + (size_t)2 * DDIM * DDIM, To);
    bias_pre<<<dim3(1801), 256, 0, stream>>>(table, rel, biasH);

    gemm8p<__bf16, 3><<<dim3(441), 512, 0, stream>>>(xb, Tqkv, bq, bk, bv,
                                                     Qb, Kb, Vb, 9);
    attn_kernel<<<dim3(64, 12), 512, 0, stream>>>(Qb, Kb, Vb, biasH, AO);
    gemm8p<float, 1><<<dim3(147), 512, 0, stream>>>(AO, To, bo, bo, bo,
                                                    out, out, out, 3);
}

// Round 9
// 161.170 us; speedup vs baseline: 1.6500x; 1.0673x over previous
//
#include <hip/hip_runtime.h>
#include <hip/hip_bf16.h>

// ---------------------------------------------------------------------------
// MultiHeadSelfAttention (Swin rel-pos bias), B=64 S=196 D=768 H=12 pd=64
// f2b ; wtrans(stacked) ; bias_pre(bf16) ; gemm8p QKV (256^2 8-phase) ;
// attn (S^T, LDS-K, software-pipelined 2-chunk online softmax) ; gemm8p O
// ---------------------------------------------------------------------------

typedef __bf16 bf16x8 __attribute__((ext_vector_type(8)));
typedef __bf16 bf16x4 __attribute__((ext_vector_type(4)));
typedef float  f32x4  __attribute__((ext_vector_type(4)));

#define MROWS 12544
#define DDIM  768
#define NHEAD 12
#define SEQ   196
#define KSTR  72         // Ksm row stride (144B, 16B-aligned; R5-proven)
#define VSTR  232        // Vts / Psm row stride (464B, 16B-aligned)

static __device__ __forceinline__ f32x4 MFMA(bf16x8 a, bf16x8 b, f32x4 c) {
    return __builtin_amdgcn_mfma_f32_16x16x32_bf16(a, b, c, 0, 0, 0);
}

static __device__ __forceinline__ void gload16(const __bf16* g, __bf16* l) {
    __builtin_amdgcn_global_load_lds(
        (const __attribute__((address_space(1))) void*)(g),
        (__attribute__((address_space(3))) void*)(l),
        16, 0, 0);
}

// ---------------- prep: fp32 -> bf16 ---------------------------------------
__global__ __launch_bounds__(256) void f2b(const float* __restrict__ in,
                                           __bf16* __restrict__ out) {
    size_t i = ((size_t)blockIdx.x * 256 + threadIdx.x) * 8;
    f32x4 a = *(const f32x4*)&in[i];
    f32x4 b = *(const f32x4*)&in[i + 4];
    bf16x8 o;
    o[0] = (__bf16)a[0]; o[1] = (__bf16)a[1]; o[2] = (__bf16)a[2]; o[3] = (__bf16)a[3];
    o[4] = (__bf16)b[0]; o[5] = (__bf16)b[1]; o[6] = (__bf16)b[2]; o[7] = (__bf16)b[3];
    *(bf16x8*)&out[i] = o;
}

// ---------------- prep: W [k][n] fp32 -> Wt [n][k] bf16 --------------------
__global__ __launch_bounds__(256) void wtrans(const float* __restrict__ W0, const float* __restrict__ W1,
                                              const float* __restrict__ W2, const float* __restrict__ W3,
                                              __bf16* __restrict__ T0, __bf16* __restrict__ T1,
                                              __bf16* __restrict__ T2, __bf16* __restrict__ T3) {
    const float* Ws[4] = {W0, W1, W2, W3};
    __bf16*      Ts[4] = {T0, T1, T2, T3};
    const float* W = Ws[blockIdx.z];
    __bf16*      T = Ts[blockIdx.z];
    __shared__ __bf16 t[32][33];
    int k0 = blockIdx.x * 32, n0 = blockIdx.y * 32;
    int c = threadIdx.x & 31, r = threadIdx.x >> 5;
#pragma unroll
    for (int i = 0; i < 4; ++i)
        t[r + i * 8][c] = (__bf16)W[(size_t)(k0 + r + i * 8) * DDIM + n0 + c];
    __syncthreads();
#pragma unroll
    for (int i = 0; i < 4; ++i)
        T[(size_t)(n0 + r + i * 8) * DDIM + k0 + c] = t[c][r + i * 8];
}

// ---------------- prep: bias[h][q][k] = table[rel[q][k]][h]  (bf16) --------
__global__ __launch_bounds__(256) void bias_pre(const float* __restrict__ table,
                                                const int* __restrict__ rel,
                                                __bf16* __restrict__ biasH) {
    int i = blockIdx.x * 256 + threadIdx.x;
    if (i < NHEAD * SEQ * SEQ) {
        int h = i / (SEQ * SEQ), qk = i - h * (SEQ * SEQ);
        biasH[i] = (__bf16)table[rel[qk] * NHEAD + h];
    }
}

// ---------------------------------------------------------------------------
// 256x256 8-phase GEMM: C = A[M][768] * Bt[N][768]^T + bias   (frozen)
// ---------------------------------------------------------------------------
template <typename OutT, int NMAT>
__global__ __launch_bounds__(512, 2) void gemm8p(const __bf16* __restrict__ A,
                                                 const __bf16* __restrict__ Bt,
                                                 const float* __restrict__ bz0,
                                                 const float* __restrict__ bz1,
                                                 const float* __restrict__ bz2,
                                                 OutT* __restrict__ Cz0,
                                                 OutT* __restrict__ Cz1,
                                                 OutT* __restrict__ Cz2,
                                                 int nbn) {
    __shared__ __bf16 As[3][256 * 64];   // 3 x 32 KiB
    __shared__ __bf16 Bs[2][256 * 64];   // 2 x 32 KiB

    const int nwg = gridDim.x, orig = blockIdx.x;
    const int qq = nwg >> 3, r8 = nwg & 7, xcd = orig & 7, lin = orig >> 3;
    const int wg = (xcd < r8 ? xcd * (qq + 1) : r8 * (qq + 1) + (xcd - r8) * qq) + lin;
    const int bm = wg / nbn, bn = wg - bm * nbn;
    const int m0 = bm * 256, n0g = bn * 256;

    const int tid = threadIdx.x, w = tid >> 6, l = tid & 63;
    const int lr = l & 15, lg = l >> 4;
    const int wrow = (w >> 2) * 128;
    const int wcol = (w & 3) * 64;

    const int srow = w * 8 + (l >> 3);
    const int scol = ((l & 7) ^ ((l >> 3) & 7)) * 8;
    const __bf16* gA = A  + (size_t)(m0 + srow) * DDIM + scol;
    const __bf16* gB = Bt + (size_t)(n0g + srow) * DDIM + scol;

#define STAGE_A(slot, h, kt)                                                      \
    do {                                                                          \
        gload16(gA + ((h) * 128 + 0) * DDIM + (kt) * 64,                          \
                &As[slot][(h) * 8192 + 0 + w * 512]);                             \
        gload16(gA + ((h) * 128 + 64) * DDIM + (kt) * 64,                         \
                &As[slot][(h) * 8192 + 4096 + w * 512]);                          \
    } while (0)
#define STAGE_B(slot, h, kt)                                                      \
    do {                                                                          \
        gload16(gB + ((h) * 128 + 0) * DDIM + (kt) * 64,                          \
                &Bs[slot][(h) * 8192 + 0 + w * 512]);                             \
        gload16(gB + ((h) * 128 + 64) * DDIM + (kt) * 64,                         \
                &Bs[slot][(h) * 8192 + 4096 + w * 512]);                          \
    } while (0)

#define AF(slot, mf, ks)                                                          \
    (*(const bf16x8*)&As[slot][(w >> 2) * 8192 + ((mf) * 16 + lr) * 64 +          \
                              ((((ks) * 4 + lg) ^ (lr & 7))) * 8])
#define BF(slot, nf, ks)                                                          \
    (*(const bf16x8*)&Bs[slot][((w & 3) >> 1) * 8192 +                            \
                              ((w & 1) * 64 + (nf) * 16 + lr) * 64 +              \
                              ((((ks) * 4 + lg) ^ (lr & 7))) * 8])

    f32x4 acc[8][4];
#pragma unroll
    for (int i = 0; i < 8; ++i)
#pragma unroll
        for (int j = 0; j < 4; ++j) acc[i][j] = (f32x4){0.f, 0.f, 0.f, 0.f};

    bf16x8 a0, a1, a2, a3;
    bf16x8 bfr00, bfr01, bfr10, bfr11, bfr20, bfr21, bfr30, bfr31;

#define DSLOAD_A(slot, mf0)                                                       \
    a0 = AF(slot, mf0, 0); a1 = AF(slot, mf0, 1);                                 \
    a2 = AF(slot, (mf0) + 1, 0); a3 = AF(slot, (mf0) + 1, 1);
#define DSLOAD_B(slot)                                                            \
    bfr00 = BF(slot, 0, 0); bfr01 = BF(slot, 0, 1);                               \
    bfr10 = BF(slot, 1, 0); bfr11 = BF(slot, 1, 1);                               \
    bfr20 = BF(slot, 2, 0); bfr21 = BF(slot, 2, 1);                               \
    bfr30 = BF(slot, 3, 0); bfr31 = BF(slot, 3, 1);
#define BARRIER_IN()                                                              \
    __builtin_amdgcn_sched_barrier(0);                                            \
    __builtin_amdgcn_s_barrier();                                                 \
    asm volatile("s_waitcnt lgkmcnt(0)" ::: "memory");                            \
    __builtin_amdgcn_sched_barrier(0);                                            \
    __builtin_amdgcn_s_setprio(1);
#define BARRIER_OUT()                                                             \
    __builtin_amdgcn_s_setprio(0);                                                \
    __builtin_amdgcn_sched_barrier(0);                                            \
    __builtin_amdgcn_s_barrier();                                                 \
    __builtin_amdgcn_sched_barrier(0);
#define MFMACL(mf0)                                                               \
    acc[mf0][0] = MFMA(a0, bfr00, acc[mf0][0]);                                   \
    acc[mf0][0] = MFMA(a1, bfr01, acc[mf0][0]);                                   \
    acc[(mf0) + 1][0] = MFMA(a2, bfr00, acc[(mf0) + 1][0]);                       \
    acc[(mf0) + 1][0] = MFMA(a3, bfr01, acc[(mf0) + 1][0]);                       \
    acc[mf0][1] = MFMA(a0, bfr10, acc[mf0][1]);                                   \
    acc[mf0][1] = MFMA(a1, bfr11, acc[mf0][1]);                                   \
    acc[(mf0) + 1][1] = MFMA(a2, bfr10, acc[(mf0) + 1][1]);                       \
    acc[(mf0) + 1][1] = MFMA(a3, bfr11, acc[(mf0) + 1][1]);                       \
    acc[mf0][2] = MFMA(a0, bfr20, acc[mf0][2]);                                   \
    acc[mf0][2] = MFMA(a1, bfr21, acc[mf0][2]);                                   \
    acc[(mf0) + 1][2] = MFMA(a2, bfr20, acc[(mf0) + 1][2]);                       \
    acc[(mf0) + 1][2] = MFMA(a3, bfr21, acc[(mf0) + 1][2]);                       \
    acc[mf0][3] = MFMA(a0, bfr30, acc[mf0][3]);                                   \
    acc[mf0][3] = MFMA(a1, bfr31, acc[mf0][3]);                                   \
    acc[(mf0) + 1][3] = MFMA(a2, bfr30, acc[(mf0) + 1][3]);                       \
    acc[(mf0) + 1][3] = MFMA(a3, bfr31, acc[(mf0) + 1][3]);

    STAGE_A(0, 0, 0); STAGE_A(0, 1, 0); STAGE_B(0, 0, 0); STAGE_B(0, 1, 0);
    STAGE_A(1, 0, 1); STAGE_A(1, 1, 1); STAGE_B(1, 0, 1); STAGE_B(1, 1, 1);
    asm volatile("s_waitcnt vmcnt(8)" ::: "memory");
    __builtin_amdgcn_s_barrier();
    __builtin_amdgcn_sched_barrier(0);

#pragma unroll
    for (int i = 0; i < 6; ++i) {
        const int s0 = (2 * i) % 3, s1 = (2 * i + 1) % 3, s2 = (2 * i + 2) % 3;
        // ---- phase 0
        DSLOAD_A(s0, 0); DSLOAD_B(0);
        if (i < 5) STAGE_A(s2, 0, 2 * i + 2);
        BARRIER_IN(); MFMACL(0); BARRIER_OUT();
        // ---- phase 1
        DSLOAD_A(s0, 2);
        if (i < 5) STAGE_A(s2, 1, 2 * i + 2);
        BARRIER_IN(); MFMACL(2); BARRIER_OUT();
        // ---- phase 2
        DSLOAD_A(s0, 4);
        if (i < 5) STAGE_B(0, 0, 2 * i + 2);
        BARRIER_IN(); MFMACL(4); BARRIER_OUT();
        // ---- phase 3
        DSLOAD_A(s0, 6);
        if (i < 5) {
            STAGE_B(0, 1, 2 * i + 2);
            asm volatile("s_waitcnt vmcnt(8)" ::: "memory");
        } else {
            asm volatile("s_waitcnt vmcnt(0)" ::: "memory");
        }
        BARRIER_IN(); MFMACL(6); BARRIER_OUT();
        // ---- phase 4
        DSLOAD_A(s1, 0); DSLOAD_B(1);
        if (i < 5) STAGE_A(s0, 0, 2 * i + 3);
        BARRIER_IN(); MFMACL(0); BARRIER_OUT();
        // ---- phase 5
        DSLOAD_A(s1, 2);
        if (i < 5) STAGE_A(s0, 1, 2 * i + 3);
        BARRIER_IN(); MFMACL(2); BARRIER_OUT();
        // ---- phase 6
        DSLOAD_A(s1, 4);
        if (i < 5) STAGE_B(1, 0, 2 * i + 3);
        BARRIER_IN(); MFMACL(4); BARRIER_OUT();
        // ---- phase 7
        DSLOAD_A(s1, 6);
        if (i < 5) {
            STAGE_B(1, 1, 2 * i + 3);
            asm volatile("s_waitcnt vmcnt(8)" ::: "memory");
        }
        BARRIER_IN(); MFMACL(6); BARRIER_OUT();
    }

    const int mat = (NMAT == 1) ? 0 : (n0g / DDIM);
    const int colbase = n0g - mat * DDIM + wcol;
    const float* bz = (mat == 0) ? bz0 : (mat == 1 ? bz1 : bz2);
    OutT* Cc = (mat == 0) ? Cz0 : (mat == 1 ? Cz1 : Cz2);
#pragma unroll
    for (int nf = 0; nf < 4; ++nf) {
        const int col = colbase + nf * 16 + lr;
        const float bb = bz[col];
#pragma unroll
        for (int mf = 0; mf < 8; ++mf) {
            const int row = m0 + wrow + mf * 16 + lg * 4;
#pragma unroll
            for (int r2 = 0; r2 < 4; ++r2)
                Cc[(size_t)(row + r2) * DDIM + col] = (OutT)(acc[mf][nf][r2] + bb);
        }
    }
#undef STAGE_A
#undef STAGE_B
#undef AF
#undef BF
#undef DSLOAD_A
#undef DSLOAD_B
#undef BARRIER_IN
#undef BARRIER_OUT
#undef MFMACL
}

// ---------------- fused attention: R5 structure + chunk pipelining ---------
// Per qt: QK1 -> SM1+Pwrite1 -> [QK2 + bias2/max2] -> PV1 -> SM2+Pwrite2 -> PV2
// The independent QK2 work covers the P1 LDS write->read round trip.
__global__ __launch_bounds__(512, 1) void attn_kernel(const __bf16* __restrict__ Qg,
                                                      const __bf16* __restrict__ Kg,
                                                      const __bf16* __restrict__ Vg,
                                                      const __bf16* __restrict__ biasH,
                                                      __bf16* __restrict__ Og) {
    __shared__ __bf16 Ksm[208 * KSTR];      // 29.3 KB
    __shared__ __bf16 Vts[64 * VSTR];       // 29.7 KB
    __shared__ __bf16 Psm[8 * 16 * VSTR];   // 58.0 KB

    const int b = blockIdx.x, h = blockIdx.y;
    const int tid = threadIdx.x, w = tid >> 6, l = tid & 63;
    const int lr = l & 15, lg = l >> 4;
    const size_t base = (size_t)(b * SEQ) * DDIM + h * 64;
    const __bf16* Kb = Kg + base;
    const __bf16* Vb = Vg + base;
    const __bf16* Qb = Qg + base;
    const __bf16* bh = biasH + (size_t)h * (SEQ * SEQ);

    // stage K rows (16B chunks)
    for (int c = tid; c < SEQ * 8; c += 512) {
        int kk = c >> 3, d8 = (c & 7) << 3;
        *(bf16x8*)&Ksm[kk * KSTR + d8] = *(const bf16x8*)&Kb[(size_t)kk * DDIM + d8];
    }
    // zero K pad rows 196..207
    for (int c = tid; c < 12 * 9; c += 512) {
        int kk = SEQ + c / 9, d8 = (c % 9) * 8;
        *(uint4*)&Ksm[kk * KSTR + d8] = make_uint4(0u, 0u, 0u, 0u);
    }
    // stage V transposed
    for (int c = tid; c < SEQ * 8; c += 512) {
        int kk = c >> 3, d8 = (c & 7) << 3;
        bf16x8 vv = *(const bf16x8*)&Vb[(size_t)kk * DDIM + d8];
#pragma unroll
        for (int j = 0; j < 8; ++j) Vts[(d8 + j) * VSTR + kk] = vv[j];
    }
    // zero Vt cols 196..223
    for (int c = tid; c < 64 * 28; c += 512)
        Vts[(c / 28) * VSTR + SEQ + (c % 28)] = (__bf16)0.f;
    // zero own-wave P cols 208..223
    __bf16* Pw = &Psm[w * 16 * VSTR];
    for (int c = l; c < 256; c += 64)
        Pw[(c >> 4) * VSTR + 208 + (c & 15)] = (__bf16)0.f;
    __syncthreads();

    for (int qt = w; qt < 13; qt += 8) {
        const int q0 = qt * 16;
        const int q = q0 + lr;
        const int qrow = min(q, SEQ - 1);
        bf16x8 bq0 = *(const bf16x8*)&Qb[(size_t)qrow * DDIM + lg * 8];
        bf16x8 bq1 = *(const bf16x8*)&Qb[(size_t)qrow * DDIM + 32 + lg * 8];

        f32x4 oa[4];
#pragma unroll
        for (int i = 0; i < 4; ++i) oa[i] = (f32x4){0.f, 0.f, 0.f, 0.f};

        // ---------------- QK chunk 1: tiles 0..7 (cols 0..127, all valid) --
        f32x4 sc1[8];
        __builtin_amdgcn_s_setprio(1);
#pragma unroll
        for (int tt = 0; tt < 8; ++tt) {
            bf16x8 kf0 = *(const bf16x8*)&Ksm[(tt * 16 + lr) * KSTR + lg * 8];
            bf16x8 kf1 = *(const bf16x8*)&Ksm[(tt * 16 + lr) * KSTR + 32 + lg * 8];
            f32x4 a = {0.f, 0.f, 0.f, 0.f};
            a = MFMA(kf0, bq0, a);
            a = MFMA(kf1, bq1, a);
            sc1[tt] = a;
        }
        __builtin_amdgcn_s_setprio(0);

        // ---------------- softmax chunk 1 ----------------------------------
        float mx = -1e30f;
#pragma unroll
        for (int tt = 0; tt < 8; ++tt) {
            bf16x4 b4 = *(const bf16x4*)&bh[(size_t)qrow * SEQ + tt * 16 + lg * 4];
#pragma unroll
            for (int r = 0; r < 4; ++r) {
                float v = sc1[tt][r] * 0.125f + (float)b4[r];
                sc1[tt][r] = v;
                mx = fmaxf(mx, v);
            }
        }
        mx = fmaxf(mx, __shfl_xor(mx, 16));
        mx = fmaxf(mx, __shfl_xor(mx, 32));
        float m_run = mx;
        float ps = 0.f;
#pragma unroll
        for (int tt = 0; tt < 8; ++tt) {
            bf16x4 pk;
#pragma unroll
            for (int r = 0; r < 4; ++r) {
                float p = __expf(sc1[tt][r] - m_run);
                ps += p;
                pk[r] = (__bf16)p;
            }
            *(bf16x4*)&Pw[lr * VSTR + tt * 16 + lg * 4] = pk;   // P cols 0..127
        }
        ps += __shfl_xor(ps, 16);
        ps += __shfl_xor(ps, 32);
        float s_run = ps;

        // ---------------- QK chunk 2: tiles 8..12 (independent of P1) ------
        f32x4 sc2[5];
        __builtin_amdgcn_s_setprio(1);
#pragma unroll
        for (int tt = 0; tt < 5; ++tt) {
            const int t = 8 + tt;
            bf16x8 kf0 = *(const bf16x8*)&Ksm[(t * 16 + lr) * KSTR + lg * 8];
            bf16x8 kf1 = *(const bf16x8*)&Ksm[(t * 16 + lr) * KSTR + 32 + lg * 8];
            f32x4 a = {0.f, 0.f, 0.f, 0.f};
            a = MFMA(kf0, bq0, a);
            a = MFMA(kf1, bq1, a);
            sc2[tt] = a;
        }
        __builtin_amdgcn_s_setprio(0);

        // bias + scale + mask + full max for chunk 2 (independent of PV1)
        float mc2 = -1e30f;
#pragma unroll
        for (int tt = 0; tt < 5; ++tt) {
            const int t = 8 + tt;
            const bool val4 = (t < 12) || (lg == 0);
            float bb[4] = {0.f, 0.f, 0.f, 0.f};
            if (val4) {
                bf16x4 b4 = *(const bf16x4*)&bh[(size_t)qrow * SEQ + t * 16 + lg * 4];
#pragma unroll
                for (int r = 0; r < 4; ++r) bb[r] = (float)b4[r];
            }
#pragma unroll
            for (int r = 0; r < 4; ++r) {
                float v = val4 ? (sc2[tt][r] * 0.125f + bb[r]) : -1e30f;
                sc2[tt][r] = v;
                mc2 = fmaxf(mc2, v);
            }
        }
        mc2 = fmaxf(mc2, __shfl_xor(mc2, 16));
        mc2 = fmaxf(mc2, __shfl_xor(mc2, 32));

        // ---------------- PV chunk 1: kt 0..3 (P cols 0..127) --------------
        __builtin_amdgcn_s_setprio(1);
#pragma unroll
        for (int kt = 0; kt < 4; ++kt) {
            bf16x8 pf = *(const bf16x8*)&Pw[lr * VSTR + kt * 32 + lg * 8];
#pragma unroll
            for (int nt = 0; nt < 4; ++nt) {
                bf16x8 vf = *(const bf16x8*)&Vts[(nt * 16 + lr) * VSTR + kt * 32 + lg * 8];
                oa[nt] = MFMA(vf, pf, oa[nt]);
            }
        }
        __builtin_amdgcn_s_setprio(0);

        // ---------------- softmax chunk 2 + rescale ------------------------
        const float mnew = fmaxf(m_run, mc2);
        const float fsc = __expf(m_run - mnew);
        m_run = mnew;
        s_run *= fsc;
#pragma unroll
        for (int i = 0; i < 4; ++i)
#pragma unroll
            for (int r = 0; r < 4; ++r) oa[i][r] *= fsc;
        ps = 0.f;
#pragma unroll
        for (int tt = 0; tt < 5; ++tt) {
            bf16x4 pk;
#pragma unroll
            for (int r = 0; r < 4; ++r) {
                float p = __expf(sc2[tt][r] - m_run);
                ps += p;
                pk[r] = (__bf16)p;
            }
            *(bf16x4*)&Pw[lr * VSTR + (8 + tt) * 16 + lg * 4] = pk;  // cols 128..207
        }
        ps += __shfl_xor(ps, 16);
        ps += __shfl_xor(ps, 32);
        s_run += ps;

        // ---------------- PV chunk 2: kt 4..6 (cols 128..223, pad zeroed) --
        __builtin_amdgcn_s_setprio(1);
#pragma unroll
        for (int kt = 4; kt < 7; ++kt) {
            bf16x8 pf = *(const bf16x8*)&Pw[lr * VSTR + kt * 32 + lg * 8];
#pragma unroll
            for (int nt = 0; nt < 4; ++nt) {
                bf16x8 vf = *(const bf16x8*)&Vts[(nt * 16 + lr) * VSTR + kt * 32 + lg * 8];
                oa[nt] = MFMA(vf, pf, oa[nt]);
            }
        }
        __builtin_amdgcn_s_setprio(0);

        const float inv = 1.f / s_run;
        if (q < SEQ) {
#pragma unroll
            for (int nt = 0; nt < 4; ++nt) {
                bf16x4 ok;
#pragma unroll
                for (int r = 0; r < 4; ++r) ok[r] = (__bf16)(oa[nt][r] * inv);
                *(bf16x4*)&Og[(size_t)(b * SEQ + q) * DDIM + h * 64 + nt * 16 + lg * 4] = ok;
            }
        }
    }
}

// ---------------------------------------------------------------------------
extern "C" void kernel_launch(void* const* d_in, const int* in_sizes, int n_in,
                              void* d_out, int out_size, void* d_ws, size_t ws_size,
                              hipStream_t stream) {
    const float* x     = (const float*)d_in[0];
    const float* Wq    = (const float*)d_in[1];
    const float* bq    = (const float*)d_in[2];
    const float* Wk    = (const float*)d_in[3];
    const float* bk    = (const float*)d_in[4];
    const float* Wv    = (const float*)d_in[5];
    const float* bv    = (const float*)d_in[6];
    const float* Wo    = (const float*)d_in[7];
    const float* bo    = (const float*)d_in[8];
    const float* table = (const float*)d_in[9];
    const int*   rel   = (const int*)d_in[10];
    float* out = (float*)d_out;

    char* ws = (char*)d_ws;
    auto alloc = [&](size_t bytes) {
        char* p = ws;
        ws += (bytes + 255) & ~(size_t)255;
        return p;
    };
    const size_t mat = (size_t)MROWS * DDIM * sizeof(__bf16);
    __bf16* xb    = (__bf16*)alloc(mat);
    __bf16* Tqkv  = (__bf16*)alloc((size_t)3 * DDIM * DDIM * 2);
    __bf16* To    = (__bf16*)alloc((size_t)DDIM * DDIM * 2);
    __bf16* Qb    = (__bf16*)alloc(mat);
    __bf16* Kb    = (__bf16*)alloc(mat);
    __bf16* Vb    = (__bf16*)alloc(mat);
    __bf16* AO    = (__bf16*)alloc(mat);
    __bf16* biasH = (__bf16*)alloc((size_t)NHEAD * SEQ * SEQ * 2);

    f2b<<<dim3(4704), 256, 0, stream>>>(x, xb);
    wtrans<<<dim3(24, 24, 4), 256, 0, stream>>>(Wq, Wk, Wv, Wo,
                                                Tqkv, Tqkv + (size_t)DDIM * DDIM,
                                                Tqkv + (size_t)2 * DDIM * DDIM, To);
    bias_pre<<<dim3(1801), 256, 0, stream>>>(table, rel, biasH);

    gemm8p<__bf16, 3><<<dim3(441), 512, 0, stream>>>(xb, Tqkv, bq, bk, bv,
                                                     Qb, Kb, Vb, 9);
    attn_kernel<<<dim3(64, 12), 512, 0, stream>>>(Qb, Kb, Vb, biasH, AO);
    gemm8p<float, 1><<<dim3(147), 512, 0, stream>>>(AO, To, bo, bo, bo,
                                                    out, out, out, 3);
}